// Round 8
// baseline (966.378 us; speedup 1.0000x reference)
//
#include <hip/hip_runtime.h>
#include <hip/hip_bf16.h>
#include <math.h>

// ---------------------------------------------------------------------------
// Round 7: gemm_bt BK=64 (half the barrier drains; R7 FFN1 was latency-bound:
// MfmaUtil 12 / VALU 24 / HBM 20 / occ 13 — nothing busy), 1D n-fastest grid
// (A-tile temporal locality across XCDs), Cs still aliased (LDS 32KB -> 5
// blocks/CU). Six cvt_transpose launches merged into one.
// ws layout unchanged (191,365,120 B).
// ---------------------------------------------------------------------------

using bf16 = __hip_bfloat16;
typedef __attribute__((ext_vector_type(8))) short frag8;
typedef __attribute__((ext_vector_type(4))) float f32x4;

static __device__ __forceinline__ float wave_sum64(float v){
  #pragma unroll
  for (int o = 32; o >= 1; o >>= 1) v += __shfl_xor(v, o, 64);
  return v;
}

static __device__ __forceinline__ void gl_lds16(const bf16* g, bf16* l){
  __builtin_amdgcn_global_load_lds((const __attribute__((address_space(1))) void*)g,
                                   (__attribute__((address_space(3))) void*)l, 16, 0, 0);
}

static __device__ __forceinline__ unsigned pack2(float a, float b){
  union { bf16 h[2]; unsigned u; } u;
  u.h[0] = __float2bfloat16(a); u.h[1] = __float2bfloat16(b);
  return u.u;
}

// merged 6-job tiled fp32->bf16 transpose. 1280 blocks.
__global__ __launch_bounds__(256) void cvt6(
    const float* s0, const float* s1, const float* s2, const float* s3,
    const float* s4, const float* s5,
    bf16* d0, bf16* d1, bf16* d2, bf16* d3, bf16* d4, bf16* d5)
{
  __shared__ float t[32][33];
  const float* srcs[6] = {s0, s1, s2, s3, s4, s5};
  bf16* dsts[6] = {d0, d1, d2, d3, d4, d5};
  const int Ks[6] = {256, 256, 256, 256, 256, 2048};
  const int Ns[6] = {256, 256, 256, 256, 2048, 256};
  const int offs[6] = {0, 64, 128, 192, 256, 768};
  int bid = blockIdx.x, j = 5;
  #pragma unroll
  for (int q = 4; q >= 0; q--) if (bid < offs[q + 1]) j = q;
  int local = bid - offs[j];
  int K = Ks[j], N = Ns[j];
  const float* src = srcs[j];
  bf16* dst = dsts[j];
  int kt = K >> 5;
  int kb = (local % kt) * 32, nb = (local / kt) * 32;
  int tx = threadIdx.x & 31, ty = threadIdx.x >> 5;
  #pragma unroll
  for (int dy = 0; dy < 32; dy += 8)
    t[ty + dy][tx] = src[(size_t)(kb + ty + dy) * N + nb + tx];
  __syncthreads();
  #pragma unroll
  for (int dy = 0; dy < 32; dy += 8)
    dst[(size_t)(nb + ty + dy) * K + kb + tx] = __float2bfloat16(t[tx][ty + dy]);
}

// embed + PE + scale -> x (bf16), LN1 -> xn (bf16). one wave/row, grid 23040.
__global__ __launch_bounds__(256) void embed_ln1(
    const int* __restrict__ src, const float* __restrict__ emb,
    const float* __restrict__ na, const float* __restrict__ nb,
    bf16* __restrict__ x, bf16* __restrict__ xn)
{
  int row  = blockIdx.x * 4 + (threadIdx.x >> 6);
  int lane = threadIdx.x & 63;
  int s = row % 360;
  int tok = src[row];
  float4 v = *(const float4*)(emb + (size_t)tok * 256 + lane * 4);
  float vv[4] = {v.x, v.y, v.z, v.w};
  if (s < 340){
    const float C = (-2.0f / 256.0f) * 13.287712379549449f;
    #pragma unroll
    for (int t = 0; t < 4; t++){
      int c = lane * 4 + t;
      float ang = (float)s * exp2f(C * (float)c);
      float pe = (c & 1) ? cosf(ang) : sinf(ang);
      vv[t] = 16.0f * vv[t] + pe;
    }
  }
  float sum = wave_sum64(vv[0] + vv[1] + vv[2] + vv[3]);
  float mu = sum * (1.0f / 256.0f);
  float d0 = vv[0]-mu, d1 = vv[1]-mu, d2 = vv[2]-mu, d3 = vv[3]-mu;
  float sq = wave_sum64(d0*d0 + d1*d1 + d2*d2 + d3*d3);
  float inv = 1.0f / (sqrtf(sq * (1.0f / 255.0f)) + 1e-6f);
  bf16 xo[4] = { __float2bfloat16(vv[0]), __float2bfloat16(vv[1]),
                 __float2bfloat16(vv[2]), __float2bfloat16(vv[3]) };
  *(uint2*)(x + (size_t)row * 256 + lane * 4) = *(uint2*)xo;
  float4 a4 = *(const float4*)(na + lane * 4);
  float4 b4 = *(const float4*)(nb + lane * 4);
  bf16 o4[4] = { __float2bfloat16(a4.x * d0 * inv + b4.x),
                 __float2bfloat16(a4.y * d1 * inv + b4.y),
                 __float2bfloat16(a4.z * d2 * inv + b4.z),
                 __float2bfloat16(a4.w * d3 * inv + b4.w) };
  *(uint2*)(xn + (size_t)row * 256 + lane * 4) = *(uint2*)o4;
}

// LN over bf16 x -> bf16 xn. one wave per row. grid 23040.
__global__ __launch_bounds__(256) void ln_k(
    const bf16* __restrict__ x, const float* __restrict__ na,
    const float* __restrict__ nb, bf16* __restrict__ xn)
{
  int row  = blockIdx.x * 4 + (threadIdx.x >> 6);
  int lane = threadIdx.x & 63;
  uint2 raw = *(const uint2*)(x + (size_t)row * 256 + lane * 4);
  bf16* xr = (bf16*)&raw;
  float v0 = __bfloat162float(xr[0]), v1 = __bfloat162float(xr[1]);
  float v2 = __bfloat162float(xr[2]), v3 = __bfloat162float(xr[3]);
  float sum = wave_sum64(v0 + v1 + v2 + v3);
  float mu = sum * (1.0f / 256.0f);
  float d0 = v0-mu, d1 = v1-mu, d2 = v2-mu, d3 = v3-mu;
  float sq = wave_sum64(d0*d0 + d1*d1 + d2*d2 + d3*d3);
  float inv = 1.0f / (sqrtf(sq * (1.0f / 255.0f)) + 1e-6f);
  float4 a4 = *(const float4*)(na + lane * 4);
  float4 b4 = *(const float4*)(nb + lane * 4);
  bf16 o4[4] = { __float2bfloat16(a4.x * d0 * inv + b4.x),
                 __float2bfloat16(a4.y * d1 * inv + b4.y),
                 __float2bfloat16(a4.z * d2 * inv + b4.z),
                 __float2bfloat16(a4.w * d3 * inv + b4.w) };
  *(uint2*)(xn + (size_t)row * 256 + lane * 4) = *(uint2*)o4;
}

// C = A[M][K] @ Bt[N][K]^T + bias. 128x128 tile, BK=64, 1D grid n-fastest.
// MODE 2: relu, bf16 row-major [M][N]
// MODE 3: bf16 residual in-place: xres[m*256+n] += acc (+bias)
// MODE 4: merged QKV (N=768): region: 0 q-layout, 1 k-layout, 2 v^T
template<int MODE>
__global__ __launch_bounds__(256) void gemm_bt(
    const bf16* __restrict__ A, int lda,
    const bf16* __restrict__ Bt, int ldb,
    const float* __restrict__ bias,
    bf16* __restrict__ outb, bf16* __restrict__ xres,
    int N, int K, int nTiles,
    const float* __restrict__ bq, const float* __restrict__ bk,
    const float* __restrict__ bv)
{
  __shared__ __align__(16) char smem[32768];   // As 16K | Bs 16K ; Cs aliases
  bf16* As = (bf16*)smem;
  bf16* Bs = (bf16*)(smem + 16384);
  bf16 (*Cs)[136] = (bf16 (*)[136])smem;
  int bi = blockIdx.x;
  int m0 = (bi / nTiles) * 128, n0 = (bi % nTiles) * 128;
  int tid = threadIdx.x;
  int wave = tid >> 6, lane = tid & 63;
  int wm = (wave >> 1) * 64, wn = (wave & 1) * 64;
  int r = lane & 15, qd = lane >> 4;

  // staging: 1024 16B-chunks per matrix per iter; chunk c = tid + j*256.
  // row = c>>3, colgrp = c&7. LDS offset = c*8 elems (row-major [128][64]).
  const bf16* ag[4]; const bf16* bg[4]; bf16* la[4]; bf16* lb[4];
  #pragma unroll
  for (int j = 0; j < 4; j++){
    int c = tid + j * 256;
    int row = c >> 3, co = c & 7;
    ag[j] = A  + (size_t)(m0 + row) * lda + co * 8;
    bg[j] = Bt + (size_t)(n0 + row) * ldb + co * 8;
    la[j] = As + (size_t)c * 8;
    lb[j] = Bs + (size_t)c * 8;
  }

  f32x4 acc[4][4];
  #pragma unroll
  for (int mt = 0; mt < 4; mt++)
    #pragma unroll
    for (int nt = 0; nt < 4; nt++) acc[mt][nt] = (f32x4){0.f, 0.f, 0.f, 0.f};

  for (int k0 = 0; k0 < K; k0 += 64){
    #pragma unroll
    for (int j = 0; j < 4; j++){ gl_lds16(ag[j], la[j]); gl_lds16(bg[j], lb[j]); }
    #pragma unroll
    for (int j = 0; j < 4; j++){ ag[j] += 64; bg[j] += 64; }
    __syncthreads();
    #pragma unroll
    for (int ph = 0; ph < 2; ph++){
      frag8 af[4], bfr[4];
      #pragma unroll
      for (int t = 0; t < 4; t++){
        af[t]  = *(const frag8*)(As + (wm + t * 16 + r) * 64 + ph * 32 + qd * 8);
        bfr[t] = *(const frag8*)(Bs + (wn + t * 16 + r) * 64 + ph * 32 + qd * 8);
      }
      #pragma unroll
      for (int mt = 0; mt < 4; mt++)
        #pragma unroll
        for (int nt = 0; nt < 4; nt++)
          acc[mt][nt] = __builtin_amdgcn_mfma_f32_16x16x32_bf16(af[mt], bfr[nt], acc[mt][nt], 0, 0, 0);
    }
    __syncthreads();
  }

  const int region = (MODE == 4) ? (n0 >> 8) : 0;
  const float* bb = (MODE == 4) ? (region == 0 ? bq : region == 1 ? bk : bv) : bias;

  #pragma unroll
  for (int half = 0; half < 2; half++){
    if ((wave >> 1) == half){
      #pragma unroll
      for (int mt = 0; mt < 4; mt++)
        #pragma unroll
        for (int nt = 0; nt < 4; nt++)
          #pragma unroll
          for (int i = 0; i < 4; i++){
            int lm = mt * 16 + qd * 4 + i;
            int ln = wn + nt * 16 + r;
            float v = acc[mt][nt][i];
            if (MODE == 2){ v += bb[n0 + ln]; v = fmaxf(v, 0.0f); }
            else if (MODE == 3){ if (bb) v += bb[n0 + ln]; }
            else { v += bb[(n0 & 255) + ln]; }
            Cs[lm][ln] = __float2bfloat16(v);
          }
    }
    __syncthreads();
    int mbase = m0 + half * 64;
    if (MODE == 2){
      int lr = tid >> 2, seg = tid & 3;
      bf16* op = outb + (size_t)(mbase + lr) * N + n0 + seg * 32;
      #pragma unroll
      for (int j = 0; j < 4; j++)
        *(uint4*)(op + j * 8) = *(uint4*)(&Cs[lr][seg * 32 + j * 8]);
    } else if (MODE == 3){
      int lr = tid >> 2, seg = tid & 3;
      bf16* op = xres + (size_t)(mbase + lr) * 256 + n0 + seg * 32;
      #pragma unroll
      for (int j = 0; j < 4; j++){
        uint4 cv = *(uint4*)(&Cs[lr][seg * 32 + j * 8]);
        uint4 xv = *(uint4*)(op + j * 8);
        bf16* ca = (bf16*)&cv; bf16* xa = (bf16*)&xv;
        bf16 o8[8];
        #pragma unroll
        for (int t = 0; t < 8; t++)
          o8[t] = __float2bfloat16(__bfloat162float(ca[t]) + __bfloat162float(xa[t]));
        *(uint4*)(op + j * 8) = *(uint4*)o8;
      }
    } else {
      if (region < 2){
        int lr = tid >> 2, seg = tid & 3;
        int m = mbase + lr;
        int b_ = m / 360, s = m - b_ * 360;
        int nnl = (n0 & 255) + seg * 32;
        int h = nnl >> 6, dk = nnl & 63;
        size_t roff = (region == 1) ? 11796480ull : 0ull;
        bf16* op = outb + roff + (((size_t)(b_ * 4 + h) * 360 + s) << 6) + dk;
        #pragma unroll
        for (int j = 0; j < 4; j++)
          *(uint4*)(op + j * 8) = *(uint4*)(&Cs[lr][seg * 32 + j * 8]);
      } else {
        int nn = tid >> 1;
        int nnl = (n0 & 255) + nn;
        int h = nnl >> 6, dk = nnl & 63;
        int msub = (tid & 1) * 32;
        #pragma unroll
        for (int j0 = 0; j0 < 32; j0 += 8){
          int m = mbase + msub + j0;
          int b_ = m / 360, s = m - b_ * 360;
          bf16 tmp[8];
          #pragma unroll
          for (int t = 0; t < 8; t++) tmp[t] = Cs[msub + j0 + t][nn];
          *(uint4*)(outb + 23592960ull + ((size_t)((b_ * 4 + h) * 64 + dk)) * 360 + s) =
              *(uint4*)tmp;
        }
      }
    }
    __syncthreads();
  }
}

// attn4: one block per (b_local,h), 512 thr / 8 waves, 3 q-tiles/wave,
// single-pass softmax (scores O(1); pad queries s=0 -> uniform). K LDS-resident.
__global__ __launch_bounds__(512) void attn4(
    const bf16* __restrict__ q, const bf16* __restrict__ kk, const bf16* __restrict__ vt,
    const int* __restrict__ src, bf16* __restrict__ ctx)
{
  __shared__ bf16 Ks[360][72];
  __shared__ bf16 Pb[8][16][48];
  int bh = blockIdx.x;
  int b = bh >> 2, h = bh & 3;
  int wave = threadIdx.x >> 6, lane = threadIdx.x & 63;
  int r = lane & 15, qd = lane >> 4;
  const bf16* qb = q  + (size_t)bh * 360 * 64;
  const bf16* kb = kk + (size_t)bh * 360 * 64;
  const bf16* vb = vt + (size_t)bh * 64 * 360;
  const int* srow = src + b * 360;

  for (int c = threadIdx.x; c < 2880; c += 512){
    int row = c >> 3, g = c & 7;
    *(uint4*)(&Ks[row][g * 8]) = *(const uint4*)(kb + row * 64 + g * 8);
  }
  __syncthreads();

  frag8 qa0[3], qa1[3];
  bool qp[3];
  float lsum[3];
  f32x4 accO[3][4];
  #pragma unroll
  for (int tl = 0; tl < 3; tl++){
    int qt = wave * 3 + tl;
    int qg = qt * 16 + r;
    int qrow = qg > 359 ? 359 : qg;
    qa0[tl] = *(const frag8*)(qb + qrow * 64 + qd * 8);
    qa1[tl] = *(const frag8*)(qb + qrow * 64 + 32 + qd * 8);
    qp[tl] = (qg < 360) && (srow[qg] == 799);
    lsum[tl] = 0.f;
    #pragma unroll
    for (int dt = 0; dt < 4; dt++) accO[tl][dt] = (f32x4){0.f, 0.f, 0.f, 0.f};
  }

  for (int kc = 0; kc < 12; kc++){
    int krow0 = kc * 32 + r;      if (krow0 > 359) krow0 = 359;
    int krow1 = kc * 32 + 16 + r; if (krow1 > 359) krow1 = 359;
    frag8 kf00 = *(const frag8*)(&Ks[krow0][qd * 8]);
    frag8 kf01 = *(const frag8*)(&Ks[krow0][32 + qd * 8]);
    frag8 kf10 = *(const frag8*)(&Ks[krow1][qd * 8]);
    frag8 kf11 = *(const frag8*)(&Ks[krow1][32 + qd * 8]);
    frag8 vf[4];
    #pragma unroll
    for (int dt = 0; dt < 4; dt++)
      vf[dt] = *(const frag8*)(vb + (size_t)(dt * 16 + r) * 360 + kc * 32 + qd * 8);

    #pragma unroll
    for (int tl = 0; tl < 3; tl++){
      f32x4 z0 = {0.f, 0.f, 0.f, 0.f}, z1 = {0.f, 0.f, 0.f, 0.f};
      z0 = __builtin_amdgcn_mfma_f32_16x16x32_bf16(kf00, qa0[tl], z0, 0, 0, 0);
      z0 = __builtin_amdgcn_mfma_f32_16x16x32_bf16(kf01, qa1[tl], z0, 0, 0, 0);
      z1 = __builtin_amdgcn_mfma_f32_16x16x32_bf16(kf10, qa0[tl], z1, 0, 0, 0);
      z1 = __builtin_amdgcn_mfma_f32_16x16x32_bf16(kf11, qa1[tl], z1, 0, 0, 0);
      float p0[4], p1[4];
      #pragma unroll
      for (int i = 0; i < 4; i++){
        int key0 = kc * 32 + qd * 4 + i;
        int key1 = key0 + 16;
        float s0 = z0[i] * 0.125f, s1 = z1[i] * 0.125f;
        if (qp[tl]){ s0 = 0.0f; s1 = 0.0f; }
        p0[i] = (key0 < 360) ? __expf(s0) : 0.0f;
        p1[i] = (key1 < 360) ? __expf(s1) : 0.0f;
        lsum[tl] += p0[i] + p1[i];
      }
      *(uint2*)(&Pb[wave][r][qd * 4])      = make_uint2(pack2(p0[0], p0[1]), pack2(p0[2], p0[3]));
      *(uint2*)(&Pb[wave][r][16 + qd * 4]) = make_uint2(pack2(p1[0], p1[1]), pack2(p1[2], p1[3]));
      asm volatile("s_waitcnt lgkmcnt(0)" ::: "memory");
      frag8 pa = *(const frag8*)(&Pb[wave][r][qd * 8]);
      #pragma unroll
      for (int dt = 0; dt < 4; dt++)
        accO[tl][dt] = __builtin_amdgcn_mfma_f32_16x16x32_bf16(pa, vf[dt], accO[tl][dt], 0, 0, 0);
      asm volatile("s_waitcnt lgkmcnt(0)" ::: "memory");
    }
  }

  #pragma unroll
  for (int tl = 0; tl < 3; tl++){
    int qt = wave * 3 + tl;
    float ls = lsum[tl];
    ls += __shfl_xor(ls, 16, 64);
    ls += __shfl_xor(ls, 32, 64);
    float invl = 1.0f / ls;
    #pragma unroll
    for (int i = 0; i < 4; i++){
      float inv_i = __shfl(invl, qd * 4 + i, 64);
      int qglob = qt * 16 + qd * 4 + i;
      if (qglob < 360){
        #pragma unroll
        for (int dt = 0; dt < 4; dt++)
          ctx[((size_t)(b * 360 + qglob)) * 256 + h * 64 + dt * 16 + r] =
              __float2bfloat16(accO[tl][dt][i] * inv_i);
      }
    }
  }
}

// head: one block per batch (grid 256, 4 waves). x rows 0..191 staged in LDS,
// wl register-resident per lane, waves sweep pairs p = wave, wave+4, ...
__global__ __launch_bounds__(256) void head_k(
    const bf16* __restrict__ x, const int* __restrict__ src,
    const float* __restrict__ wl, const float* __restrict__ bl,
    float* __restrict__ out)
{
  __shared__ bf16 Xs[192][264];
  int b = blockIdx.x;
  int tid = threadIdx.x;
  int wave = tid >> 6, lane = tid & 63;
  int g = lane >> 3, sub = lane & 7;

  const bf16* xb = x + (size_t)b * 360 * 256;
  for (int it = 0; it < 24; it++){
    int idx = tid + it * 256;
    int row = idx >> 5, col = idx & 31;
    *(uint4*)(&Xs[row][col * 8]) = *(const uint4*)(xb + row * 256 + col * 8);
  }

  float wv[96];
  {
    const float4* wr4 = (const float4*)(wl + (size_t)(g * 256 + sub * 32) * 3);
    #pragma unroll
    for (int c = 0; c < 24; c++) *(float4*)(&wv[c * 4]) = wr4[c];
  }
  float bl0 = bl[0], bl1 = bl[1], bl2 = bl[2];
  const int* sr = src + b * 360;
  __syncthreads();

  for (int p = wave; p < 91; p += 4){
    int i = 0, rem = p;
    while (rem >= 13 - i){ rem -= 13 - i; i++; }
    int j = i + 1 + rem;
    int base = 12 * i - (i * (i - 1)) / 2;
    int pe = base + (j - i) - 1;
    int eb = 28 + 2 * pe;

    int idxg;
    if (g == 0) idxg = 2 * i;
    else if (g == 1) idxg = 2 * i + 1;
    else if (g == 2) idxg = 2 * j;
    else if (g == 3) idxg = 2 * j + 1;
    else idxg = eb + (g - 4);
    bool zm = !(g >= 4 && j == 13);

    uint4 xv[4];
    #pragma unroll
    for (int c = 0; c < 4; c++) xv[c] = *(uint4*)(&Xs[idxg][sub * 32 + c * 8]);
    const bf16* xa = (const bf16*)xv;
    float a0 = 0.f, a1 = 0.f, a2 = 0.f;
    #pragma unroll
    for (int t = 0; t < 32; t++){
      float f = zm ? __bfloat162float(xa[t]) : 0.0f;
      a0 += f * wv[t * 3 + 0];
      a1 += f * wv[t * 3 + 1];
      a2 += f * wv[t * 3 + 2];
    }
    #pragma unroll
    for (int o = 1; o < 64; o <<= 1){
      a0 += __shfl_xor(a0, o, 64);
      a1 += __shfl_xor(a1, o, 64);
      a2 += __shfl_xor(a2, o, 64);
    }
    if (lane == 0){
      int ti = sr[2 * i], ai = sr[2 * i + 1], tj = sr[2 * j], aj = sr[2 * j + 1];
      bool c1 = (ai == 2) || (aj == 2);
      bool c2 = (tj == 1) || (ai == 1) || (aj == 1);
      bool c3 = (ti == 799) || (tj == 799) || (ai == 0) || (aj == 0);
      bool c4 = false;
      if (j < 13){
        int es = 28 + 4 * pe;
        c4 = (sr[es] == 1) || (sr[es + 1] == 1) || (sr[es + 2] == 1) || (sr[es + 3] == 1);
      }
      bool m1 = c3 || c4, m2 = m1 || c2, m3 = m2 || c1;
      float* op = out + ((size_t)b * 91 + p) * 3;
      op[0] = m1 ? -1.0e9f : (a0 + bl0);
      op[1] = m2 ? -1.0e9f : (a1 + bl1);
      op[2] = m3 ? -1.0e9f : (a2 + bl2);
    }
  }
}

extern "C" void kernel_launch(void* const* d_in, const int* in_sizes, int n_in,
                              void* d_out, int out_size, void* d_ws, size_t ws_size,
                              hipStream_t stream)
{
  const int*   src = (const int*)  d_in[0];
  const float* emb = (const float*)d_in[1];
  const float* wq  = (const float*)d_in[2];  const float* bq = (const float*)d_in[3];
  const float* wk  = (const float*)d_in[4];  const float* bk = (const float*)d_in[5];
  const float* wv  = (const float*)d_in[6];  const float* bv = (const float*)d_in[7];
  const float* wo  = (const float*)d_in[8];  const float* bo = (const float*)d_in[9];
  const float* n1a = (const float*)d_in[10]; const float* n1b = (const float*)d_in[11];
  const float* n2a = (const float*)d_in[12]; const float* n2b = (const float*)d_in[13];
  const float* w1  = (const float*)d_in[14]; const float* b1 = (const float*)d_in[15];
  const float* w2  = (const float*)d_in[16]; const float* b2 = (const float*)d_in[17];
  const float* wl  = (const float*)d_in[18]; const float* bl = (const float*)d_in[19];
  float* out = (float*)d_out;

  if (ws_size < 191365120ull) return;

  char* ws = (char*)d_ws;
  bf16* x   = (bf16*)(ws);
  bf16* xn  = (bf16*)(ws + 47185920ull);
  char* R   = ws + 94371840ull;
  bf16* qh   = (bf16*)(R);
  bf16* kh   = (bf16*)(R + 23592960ull);
  bf16* vth  = (bf16*)(R + 47185920ull);
  bf16* ctxh = (bf16*)(R + 70778880ull);
  bf16* hbuf = (bf16*)(R);
  bf16* wT   = (bf16*)(ws + 188743680ull);
  bf16* wqT = wT;
  bf16* wkT = wT + 65536;
  bf16* wvT = wT + 131072;
  bf16* woT = wT + 196608;
  bf16* w1T = wT + 262144;
  bf16* w2T = w1T + 524288;

  cvt6<<<1280, 256, 0, stream>>>(wq, wk, wv, wo, w1, w2, wqT, wkT, wvT, woT, w1T, w2T);

  embed_ln1<<<23040, 256, 0, stream>>>(src, emb, n1a, n1b, x, xn);

  for (int half = 0; half < 2; half++){
    size_t ro = (size_t)half * 46080;
    const bf16* xnh = xn + ro * 256;
    gemm_bt<4><<<2160, 256, 0, stream>>>(xnh, 256, wqT, 256, nullptr, qh, nullptr,
                                         768, 256, 6, bq, bk, bv);
    attn4<<<512, 512, 0, stream>>>(qh, kh, vth, src + ro, ctxh);
    gemm_bt<3><<<720, 256, 0, stream>>>(ctxh, 256, woT, 256, bo, nullptr, x + ro * 256,
                                        256, 256, 2, nullptr, nullptr, nullptr);
  }

  ln_k<<<23040, 256, 0, stream>>>(x, n2a, n2b, xn);

  for (int mc = 0; mc < 4; mc++){
    const bf16* xnc = xn + (size_t)mc * 23040 * 256;
    bf16* xc = x + (size_t)mc * 23040 * 256;
    gemm_bt<2><<<2880, 256, 0, stream>>>(xnc, 256, w1T, 256, b1, hbuf, nullptr,
                                         2048, 256, 16, nullptr, nullptr, nullptr);
    gemm_bt<3><<<360, 256, 0, stream>>>(hbuf, 2048, w2T, 2048, b2, nullptr, xc,
                                        256, 2048, 2, nullptr, nullptr, nullptr);
  }

  head_k<<<256, 256, 0, stream>>>(x, src, wl, bl, out);
}

// Round 10
// 851.450 us; speedup vs baseline: 1.1350x; 1.1350x over previous
//
#include <hip/hip_runtime.h>
#include <hip/hip_bf16.h>
#include <math.h>

// ---------------------------------------------------------------------------
// Round 9: R8 + one fix: gemm_f8 MODE2 epilogue store used lr=tid>>1 (0..127)
// on a 64-row half-tile -> LDS OOB reads + garbage stores into neighboring h8
// rows (fp8 0x7F = NaN) -> NaN cascade. Now lr=tid>>2, 32B/thread.
// R8 content: XOR-swizzled LDS in both GEMMs; fp8-e4m3 FFN (ln2->fp8,
// w1/w2 fp8, mfma fp8_fp8). ws layout 191,365,120 B unchanged.
// ---------------------------------------------------------------------------

using bf16 = __hip_bfloat16;
typedef __attribute__((ext_vector_type(8))) short frag8;
typedef __attribute__((ext_vector_type(4))) float f32x4;
typedef long long i64;
typedef unsigned char uchar;

static __device__ __forceinline__ float wave_sum64(float v){
  #pragma unroll
  for (int o = 32; o >= 1; o >>= 1) v += __shfl_xor(v, o, 64);
  return v;
}

static __device__ __forceinline__ void gl_lds16(const void* g, void* l){
  __builtin_amdgcn_global_load_lds((const __attribute__((address_space(1))) void*)g,
                                   (__attribute__((address_space(3))) void*)l, 16, 0, 0);
}

static __device__ __forceinline__ unsigned pack2(float a, float b){
  union { bf16 h[2]; unsigned u; } u;
  u.h[0] = __float2bfloat16(a); u.h[1] = __float2bfloat16(b);
  return u.u;
}

static __device__ __forceinline__ uchar f2f8(float v){
  return (uchar)(__builtin_amdgcn_cvt_pk_fp8_f32(v, 0.f, 0, false) & 0xff);
}
static __device__ __forceinline__ unsigned pack4_fp8(float a, float b, float c, float d){
  int v = __builtin_amdgcn_cvt_pk_fp8_f32(a, b, 0, false);
  v = __builtin_amdgcn_cvt_pk_fp8_f32(c, d, v, true);
  return (unsigned)v;
}

// merged weight prep: jobs 0-3 bf16 256x256 transposes (wq,wk,wv,wo),
// jobs 4,5: w1 [256][2048] / w2 [2048][256] -> fp8 transposed. 1280 blocks.
__global__ __launch_bounds__(256) void cvt_all(
    const float* s0, const float* s1, const float* s2, const float* s3,
    const float* s4, const float* s5,
    bf16* d0, bf16* d1, bf16* d2, bf16* d3, uchar* d4, uchar* d5)
{
  __shared__ float t[32][33];
  const float* srcs[6] = {s0, s1, s2, s3, s4, s5};
  const int Ks[6] = {256, 256, 256, 256, 256, 2048};
  const int Ns[6] = {256, 256, 256, 256, 2048, 256};
  const int offs[7] = {0, 64, 128, 192, 256, 768, 1280};
  int bid = blockIdx.x, j = 5;
  #pragma unroll
  for (int q = 4; q >= 0; q--) if (bid < offs[q + 1]) j = q;
  int local = bid - offs[j];
  int K = Ks[j], N = Ns[j];
  const float* src = srcs[j];
  int kt = K >> 5;
  int kb = (local % kt) * 32, nb = (local / kt) * 32;
  int tx = threadIdx.x & 31, ty = threadIdx.x >> 5;
  #pragma unroll
  for (int dy = 0; dy < 32; dy += 8)
    t[ty + dy][tx] = src[(size_t)(kb + ty + dy) * N + nb + tx];
  __syncthreads();
  if (j < 4){
    bf16* dst = (j == 0) ? d0 : (j == 1) ? d1 : (j == 2) ? d2 : d3;
    #pragma unroll
    for (int dy = 0; dy < 32; dy += 8)
      dst[(size_t)(nb + ty + dy) * K + kb + tx] = __float2bfloat16(t[tx][ty + dy]);
  } else {
    uchar* dst = (j == 4) ? d4 : d5;
    #pragma unroll
    for (int dy = 0; dy < 32; dy += 8)
      dst[(size_t)(nb + ty + dy) * K + kb + tx] = f2f8(t[tx][ty + dy]);
  }
}

// embed + PE + scale -> x (bf16), LN1 -> xn (bf16). one wave/row, grid 23040.
__global__ __launch_bounds__(256) void embed_ln1(
    const int* __restrict__ src, const float* __restrict__ emb,
    const float* __restrict__ na, const float* __restrict__ nb,
    bf16* __restrict__ x, bf16* __restrict__ xn)
{
  int row  = blockIdx.x * 4 + (threadIdx.x >> 6);
  int lane = threadIdx.x & 63;
  int s = row % 360;
  int tok = src[row];
  float4 v = *(const float4*)(emb + (size_t)tok * 256 + lane * 4);
  float vv[4] = {v.x, v.y, v.z, v.w};
  if (s < 340){
    const float C = (-2.0f / 256.0f) * 13.287712379549449f;
    #pragma unroll
    for (int t = 0; t < 4; t++){
      int c = lane * 4 + t;
      float ang = (float)s * exp2f(C * (float)c);
      float pe = (c & 1) ? cosf(ang) : sinf(ang);
      vv[t] = 16.0f * vv[t] + pe;
    }
  }
  float sum = wave_sum64(vv[0] + vv[1] + vv[2] + vv[3]);
  float mu = sum * (1.0f / 256.0f);
  float d0 = vv[0]-mu, d1 = vv[1]-mu, d2 = vv[2]-mu, d3 = vv[3]-mu;
  float sq = wave_sum64(d0*d0 + d1*d1 + d2*d2 + d3*d3);
  float inv = 1.0f / (sqrtf(sq * (1.0f / 255.0f)) + 1e-6f);
  bf16 xo[4] = { __float2bfloat16(vv[0]), __float2bfloat16(vv[1]),
                 __float2bfloat16(vv[2]), __float2bfloat16(vv[3]) };
  *(uint2*)(x + (size_t)row * 256 + lane * 4) = *(uint2*)xo;
  float4 a4 = *(const float4*)(na + lane * 4);
  float4 b4 = *(const float4*)(nb + lane * 4);
  bf16 o4[4] = { __float2bfloat16(a4.x * d0 * inv + b4.x),
                 __float2bfloat16(a4.y * d1 * inv + b4.y),
                 __float2bfloat16(a4.z * d2 * inv + b4.z),
                 __float2bfloat16(a4.w * d3 * inv + b4.w) };
  *(uint2*)(xn + (size_t)row * 256 + lane * 4) = *(uint2*)o4;
}

// LN2 over bf16 x -> fp8 xn8. one wave per row. grid 23040.
__global__ __launch_bounds__(256) void ln_k8(
    const bf16* __restrict__ x, const float* __restrict__ na,
    const float* __restrict__ nb, uchar* __restrict__ xn8)
{
  int row  = blockIdx.x * 4 + (threadIdx.x >> 6);
  int lane = threadIdx.x & 63;
  uint2 raw = *(const uint2*)(x + (size_t)row * 256 + lane * 4);
  bf16* xr = (bf16*)&raw;
  float v0 = __bfloat162float(xr[0]), v1 = __bfloat162float(xr[1]);
  float v2 = __bfloat162float(xr[2]), v3 = __bfloat162float(xr[3]);
  float sum = wave_sum64(v0 + v1 + v2 + v3);
  float mu = sum * (1.0f / 256.0f);
  float d0 = v0-mu, d1 = v1-mu, d2 = v2-mu, d3 = v3-mu;
  float sq = wave_sum64(d0*d0 + d1*d1 + d2*d2 + d3*d3);
  float inv = 1.0f / (sqrtf(sq * (1.0f / 255.0f)) + 1e-6f);
  float4 a4 = *(const float4*)(na + lane * 4);
  float4 b4 = *(const float4*)(nb + lane * 4);
  unsigned u = pack4_fp8(a4.x * d0 * inv + b4.x, a4.y * d1 * inv + b4.y,
                         a4.z * d2 * inv + b4.z, a4.w * d3 * inv + b4.w);
  *(unsigned*)(xn8 + (size_t)row * 256 + lane * 4) = u;
}

// bf16 GEMM: C = A[M][K] @ Bt[N][K]^T. 128x128 tile, BK=64, swizzled LDS.
// MODE 3: bf16 residual in-place: xres[m*256+n] += acc (+bias)
// MODE 4: merged QKV (N=768): region: 0 q-layout, 1 k-layout, 2 v^T
template<int MODE>
__global__ __launch_bounds__(256) void gemm_bt(
    const bf16* __restrict__ A, int lda,
    const bf16* __restrict__ Bt, int ldb,
    const float* __restrict__ bias,
    bf16* __restrict__ outb, bf16* __restrict__ xres,
    int N, int K, int nTiles,
    const float* __restrict__ bq, const float* __restrict__ bk,
    const float* __restrict__ bv)
{
  __shared__ __align__(16) char smem[32768];
  bf16* As = (bf16*)smem;
  bf16* Bs = (bf16*)(smem + 16384);
  bf16 (*Cs)[136] = (bf16 (*)[136])smem;
  int bi = blockIdx.x;
  int m0 = (bi / nTiles) * 128, n0 = (bi % nTiles) * 128;
  int tid = threadIdx.x;
  int wave = tid >> 6, lane = tid & 63;
  int wm = (wave >> 1) * 64, wn = (wave & 1) * 64;
  int r = lane & 15, qd = lane >> 4;

  const bf16* ag[4]; const bf16* bg[4]; bf16* la[4]; bf16* lb[4];
  #pragma unroll
  for (int j = 0; j < 4; j++){
    int c = tid + j * 256;
    int row = c >> 3, pl = c & 7;
    int lco = pl ^ (row & 7);
    ag[j] = A  + (size_t)(m0 + row) * lda + lco * 8;
    bg[j] = Bt + (size_t)(n0 + row) * ldb + lco * 8;
    la[j] = As + (size_t)c * 8;
    lb[j] = Bs + (size_t)c * 8;
  }

  f32x4 acc[4][4];
  #pragma unroll
  for (int mt = 0; mt < 4; mt++)
    #pragma unroll
    for (int nt = 0; nt < 4; nt++) acc[mt][nt] = (f32x4){0.f, 0.f, 0.f, 0.f};

  for (int k0 = 0; k0 < K; k0 += 64){
    #pragma unroll
    for (int j = 0; j < 4; j++){ gl_lds16(ag[j], la[j]); gl_lds16(bg[j], lb[j]); }
    #pragma unroll
    for (int j = 0; j < 4; j++){ ag[j] += 64; bg[j] += 64; }
    __syncthreads();
    #pragma unroll
    for (int ph = 0; ph < 2; ph++){
      frag8 af[4], bfr[4];
      #pragma unroll
      for (int t = 0; t < 4; t++){
        int sw = ((ph * 4 + qd) ^ (r & 7)) * 8;
        af[t]  = *(const frag8*)(As + (wm + t * 16 + r) * 64 + sw);
        bfr[t] = *(const frag8*)(Bs + (wn + t * 16 + r) * 64 + sw);
      }
      #pragma unroll
      for (int mt = 0; mt < 4; mt++)
        #pragma unroll
        for (int nt = 0; nt < 4; nt++)
          acc[mt][nt] = __builtin_amdgcn_mfma_f32_16x16x32_bf16(af[mt], bfr[nt], acc[mt][nt], 0, 0, 0);
    }
    __syncthreads();
  }

  const int region = (MODE == 4) ? (n0 >> 8) : 0;
  const float* bb = (MODE == 4) ? (region == 0 ? bq : region == 1 ? bk : bv) : bias;

  #pragma unroll
  for (int half = 0; half < 2; half++){
    if ((wave >> 1) == half){
      #pragma unroll
      for (int mt = 0; mt < 4; mt++)
        #pragma unroll
        for (int nt = 0; nt < 4; nt++)
          #pragma unroll
          for (int i = 0; i < 4; i++){
            int lm = mt * 16 + qd * 4 + i;
            int ln = wn + nt * 16 + r;
            float v = acc[mt][nt][i];
            if (MODE == 3){ if (bb) v += bb[n0 + ln]; }
            else { v += bb[(n0 & 255) + ln]; }
            Cs[lm][ln] = __float2bfloat16(v);
          }
    }
    __syncthreads();
    int mbase = m0 + half * 64;
    if (MODE == 3){
      int lr = tid >> 2, seg = tid & 3;
      bf16* op = xres + (size_t)(mbase + lr) * 256 + n0 + seg * 32;
      #pragma unroll
      for (int j = 0; j < 4; j++){
        uint4 cv = *(uint4*)(&Cs[lr][seg * 32 + j * 8]);
        uint4 xv = *(uint4*)(op + j * 8);
        bf16* ca = (bf16*)&cv; bf16* xa = (bf16*)&xv;
        bf16 o8[8];
        #pragma unroll
        for (int t = 0; t < 8; t++)
          o8[t] = __float2bfloat16(__bfloat162float(ca[t]) + __bfloat162float(xa[t]));
        *(uint4*)(op + j * 8) = *(uint4*)o8;
      }
    } else {
      if (region < 2){
        int lr = tid >> 2, seg = tid & 3;
        int m = mbase + lr;
        int b_ = m / 360, s = m - b_ * 360;
        int nnl = (n0 & 255) + seg * 32;
        int h = nnl >> 6, dk = nnl & 63;
        size_t roff = (region == 1) ? 11796480ull : 0ull;
        bf16* op = outb + roff + (((size_t)(b_ * 4 + h) * 360 + s) << 6) + dk;
        #pragma unroll
        for (int j = 0; j < 4; j++)
          *(uint4*)(op + j * 8) = *(uint4*)(&Cs[lr][seg * 32 + j * 8]);
      } else {
        int nn = tid >> 1;
        int nnl = (n0 & 255) + nn;
        int h = nnl >> 6, dk = nnl & 63;
        int msub = (tid & 1) * 32;
        #pragma unroll
        for (int j0 = 0; j0 < 32; j0 += 8){
          int m = mbase + msub + j0;
          int b_ = m / 360, s = m - b_ * 360;
          bf16 tmp[8];
          #pragma unroll
          for (int t = 0; t < 8; t++) tmp[t] = Cs[msub + j0 + t][nn];
          *(uint4*)(outb + 23592960ull + ((size_t)((b_ * 4 + h) * 64 + dk)) * 360 + s) =
              *(uint4*)tmp;
        }
      }
    }
    __syncthreads();
  }
}

// fp8 GEMM: C = A[M][K](e4m3) @ Bt[N][K]^T(e4m3). 128x128 tile, BK=64,
// 16B-granule XOR swizzle (key row&3).
// MODE 2: relu -> fp8 row-major [M][N]
// MODE 3: bf16 residual in-place += acc (+bias)
template<int MODE>
__global__ __launch_bounds__(256) void gemm_f8(
    const uchar* __restrict__ A, int lda,
    const uchar* __restrict__ Bt, int ldb,
    const float* __restrict__ bias,
    uchar* __restrict__ out8, bf16* __restrict__ xres,
    int N, int K, int nTiles)
{
  __shared__ __align__(16) char smem[17408];   // As 8K | Bs 8K ; Cs/Cs8 alias
  uchar* As = (uchar*)smem;
  uchar* Bs = (uchar*)(smem + 8192);
  bf16 (*Cs)[136] = (bf16 (*)[136])smem;
  uchar (*Cs8)[144] = (uchar (*)[144])smem;
  int bi = blockIdx.x;
  int m0 = (bi / nTiles) * 128, n0 = (bi % nTiles) * 128;
  int tid = threadIdx.x;
  int wave = tid >> 6, lane = tid & 63;
  int wm = (wave >> 1) * 64, wn = (wave & 1) * 64;
  int r = lane & 15, qd = lane >> 4;

  const uchar* ag[2]; const uchar* bg[2]; uchar* la[2]; uchar* lb[2];
  #pragma unroll
  for (int j = 0; j < 2; j++){
    int c = tid + j * 256;
    int row = c >> 2, pp = c & 3;
    int lco = pp ^ (row & 3);
    ag[j] = A  + (size_t)(m0 + row) * lda + lco * 16;
    bg[j] = Bt + (size_t)(n0 + row) * ldb + lco * 16;
    la[j] = As + (size_t)c * 16;
    lb[j] = Bs + (size_t)c * 16;
  }

  f32x4 acc[4][4];
  #pragma unroll
  for (int mt = 0; mt < 4; mt++)
    #pragma unroll
    for (int nt = 0; nt < 4; nt++) acc[mt][nt] = (f32x4){0.f, 0.f, 0.f, 0.f};

  for (int k0 = 0; k0 < K; k0 += 64){
    #pragma unroll
    for (int j = 0; j < 2; j++){ gl_lds16(ag[j], la[j]); gl_lds16(bg[j], lb[j]); }
    #pragma unroll
    for (int j = 0; j < 2; j++){ ag[j] += 64; bg[j] += 64; }
    __syncthreads();
    #pragma unroll
    for (int ph = 0; ph < 2; ph++){
      int l16 = ph * 2 + (qd >> 1);
      int woff = (qd & 1) * 8;
      i64 af[4], bfr[4];
      #pragma unroll
      for (int t = 0; t < 4; t++){
        int swA = ((l16 ^ (r & 3)) * 16) + woff;
        af[t]  = *(const i64*)(As + (wm + t * 16 + r) * 64 + swA);
        bfr[t] = *(const i64*)(Bs + (wn + t * 16 + r) * 64 + swA);
      }
      #pragma unroll
      for (int mt = 0; mt < 4; mt++)
        #pragma unroll
        for (int nt = 0; nt < 4; nt++)
          acc[mt][nt] = __builtin_amdgcn_mfma_f32_16x16x32_fp8_fp8(af[mt], bfr[nt], acc[mt][nt], 0, 0, 0);
    }
    __syncthreads();
  }

  #pragma unroll
  for (int half = 0; half < 2; half++){
    if ((wave >> 1) == half){
      #pragma unroll
      for (int mt = 0; mt < 4; mt++)
        #pragma unroll
        for (int nt = 0; nt < 4; nt++)
          #pragma unroll
          for (int i = 0; i < 4; i++){
            int lm = mt * 16 + qd * 4 + i;
            int ln = wn + nt * 16 + r;
            float v = acc[mt][nt][i] + bias[n0 + ln];
            if (MODE == 2){
              Cs8[lm][ln] = f2f8(fmaxf(v, 0.0f));
            } else {
              Cs[lm][ln] = __float2bfloat16(v);
            }
          }
    }
    __syncthreads();
    int mbase = m0 + half * 64;
    if (MODE == 2){
      // 64 rows x 128 B = 8192 B; 256 thr x 32 B. lr=tid>>2 (0..63), seg=tid&3.
      int lr = tid >> 2, seg = tid & 3;
      uchar* op = out8 + (size_t)(mbase + lr) * N + n0 + seg * 32;
      #pragma unroll
      for (int j = 0; j < 2; j++)
        *(uint4*)(op + j * 16) = *(uint4*)(&Cs8[lr][seg * 32 + j * 16]);
    } else {
      int lr = tid >> 2, seg = tid & 3;
      bf16* op = xres + (size_t)(mbase + lr) * 256 + n0 + seg * 32;
      #pragma unroll
      for (int j = 0; j < 4; j++){
        uint4 cv = *(uint4*)(&Cs[lr][seg * 32 + j * 8]);
        uint4 xv = *(uint4*)(op + j * 8);
        bf16* ca = (bf16*)&cv; bf16* xa = (bf16*)&xv;
        bf16 o8[8];
        #pragma unroll
        for (int t = 0; t < 8; t++)
          o8[t] = __float2bfloat16(__bfloat162float(ca[t]) + __bfloat162float(xa[t]));
        *(uint4*)(op + j * 8) = *(uint4*)o8;
      }
    }
    __syncthreads();
  }
}

// attn4: one block per (b_local,h), 512 thr / 8 waves, 3 q-tiles/wave,
// single-pass softmax (scores O(1); pad queries s=0 -> uniform). K LDS-resident.
__global__ __launch_bounds__(512) void attn4(
    const bf16* __restrict__ q, const bf16* __restrict__ kk, const bf16* __restrict__ vt,
    const int* __restrict__ src, bf16* __restrict__ ctx)
{
  __shared__ bf16 Ks[360][72];
  __shared__ bf16 Pb[8][16][48];
  int bh = blockIdx.x;
  int b = bh >> 2, h = bh & 3;
  int wave = threadIdx.x >> 6, lane = threadIdx.x & 63;
  int r = lane & 15, qd = lane >> 4;
  const bf16* qb = q  + (size_t)bh * 360 * 64;
  const bf16* kb = kk + (size_t)bh * 360 * 64;
  const bf16* vb = vt + (size_t)bh * 64 * 360;
  const int* srow = src + b * 360;

  for (int c = threadIdx.x; c < 2880; c += 512){
    int row = c >> 3, g = c & 7;
    *(uint4*)(&Ks[row][g * 8]) = *(const uint4*)(kb + row * 64 + g * 8);
  }
  __syncthreads();

  frag8 qa0[3], qa1[3];
  bool qp[3];
  float lsum[3];
  f32x4 accO[3][4];
  #pragma unroll
  for (int tl = 0; tl < 3; tl++){
    int qt = wave * 3 + tl;
    int qg = qt * 16 + r;
    int qrow = qg > 359 ? 359 : qg;
    qa0[tl] = *(const frag8*)(qb + qrow * 64 + qd * 8);
    qa1[tl] = *(const frag8*)(qb + qrow * 64 + 32 + qd * 8);
    qp[tl] = (qg < 360) && (srow[qg] == 799);
    lsum[tl] = 0.f;
    #pragma unroll
    for (int dt = 0; dt < 4; dt++) accO[tl][dt] = (f32x4){0.f, 0.f, 0.f, 0.f};
  }

  for (int kc = 0; kc < 12; kc++){
    int krow0 = kc * 32 + r;      if (krow0 > 359) krow0 = 359;
    int krow1 = kc * 32 + 16 + r; if (krow1 > 359) krow1 = 359;
    frag8 kf00 = *(const frag8*)(&Ks[krow0][qd * 8]);
    frag8 kf01 = *(const frag8*)(&Ks[krow0][32 + qd * 8]);
    frag8 kf10 = *(const frag8*)(&Ks[krow1][qd * 8]);
    frag8 kf11 = *(const frag8*)(&Ks[krow1][32 + qd * 8]);
    frag8 vf[4];
    #pragma unroll
    for (int dt = 0; dt < 4; dt++)
      vf[dt] = *(const frag8*)(vb + (size_t)(dt * 16 + r) * 360 + kc * 32 + qd * 8);

    #pragma unroll
    for (int tl = 0; tl < 3; tl++){
      f32x4 z0 = {0.f, 0.f, 0.f, 0.f}, z1 = {0.f, 0.f, 0.f, 0.f};
      z0 = __builtin_amdgcn_mfma_f32_16x16x32_bf16(kf00, qa0[tl], z0, 0, 0, 0);
      z0 = __builtin_amdgcn_mfma_f32_16x16x32_bf16(kf01, qa1[tl], z0, 0, 0, 0);
      z1 = __builtin_amdgcn_mfma_f32_16x16x32_bf16(kf10, qa0[tl], z1, 0, 0, 0);
      z1 = __builtin_amdgcn_mfma_f32_16x16x32_bf16(kf11, qa1[tl], z1, 0, 0, 0);
      float p0[4], p1[4];
      #pragma unroll
      for (int i = 0; i < 4; i++){
        int key0 = kc * 32 + qd * 4 + i;
        int key1 = key0 + 16;
        float s0 = z0[i] * 0.125f, s1 = z1[i] * 0.125f;
        if (qp[tl]){ s0 = 0.0f; s1 = 0.0f; }
        p0[i] = (key0 < 360) ? __expf(s0) : 0.0f;
        p1[i] = (key1 < 360) ? __expf(s1) : 0.0f;
        lsum[tl] += p0[i] + p1[i];
      }
      *(uint2*)(&Pb[wave][r][qd * 4])      = make_uint2(pack2(p0[0], p0[1]), pack2(p0[2], p0[3]));
      *(uint2*)(&Pb[wave][r][16 + qd * 4]) = make_uint2(pack2(p1[0], p1[1]), pack2(p1[2], p1[3]));
      asm volatile("s_waitcnt lgkmcnt(0)" ::: "memory");
      frag8 pa = *(const frag8*)(&Pb[wave][r][qd * 8]);
      #pragma unroll
      for (int dt = 0; dt < 4; dt++)
        accO[tl][dt] = __builtin_amdgcn_mfma_f32_16x16x32_bf16(pa, vf[dt], accO[tl][dt], 0, 0, 0);
      asm volatile("s_waitcnt lgkmcnt(0)" ::: "memory");
    }
  }

  #pragma unroll
  for (int tl = 0; tl < 3; tl++){
    int qt = wave * 3 + tl;
    float ls = lsum[tl];
    ls += __shfl_xor(ls, 16, 64);
    ls += __shfl_xor(ls, 32, 64);
    float invl = 1.0f / ls;
    #pragma unroll
    for (int i = 0; i < 4; i++){
      float inv_i = __shfl(invl, qd * 4 + i, 64);
      int qglob = qt * 16 + qd * 4 + i;
      if (qglob < 360){
        #pragma unroll
        for (int dt = 0; dt < 4; dt++)
          ctx[((size_t)(b * 360 + qglob)) * 256 + h * 64 + dt * 16 + r] =
              __float2bfloat16(accO[tl][dt][i] * inv_i);
      }
    }
  }
}

// head: one block per batch (grid 256, 4 waves). x rows 0..191 staged in LDS,
// wl register-resident per lane, waves sweep pairs p = wave, wave+4, ...
__global__ __launch_bounds__(256) void head_k(
    const bf16* __restrict__ x, const int* __restrict__ src,
    const float* __restrict__ wl, const float* __restrict__ bl,
    float* __restrict__ out)
{
  __shared__ bf16 Xs[192][264];
  int b = blockIdx.x;
  int tid = threadIdx.x;
  int wave = tid >> 6, lane = tid & 63;
  int g = lane >> 3, sub = lane & 7;

  const bf16* xb = x + (size_t)b * 360 * 256;
  for (int it = 0; it < 24; it++){
    int idx = tid + it * 256;
    int row = idx >> 5, col = idx & 31;
    *(uint4*)(&Xs[row][col * 8]) = *(const uint4*)(xb + row * 256 + col * 8);
  }

  float wv[96];
  {
    const float4* wr4 = (const float4*)(wl + (size_t)(g * 256 + sub * 32) * 3);
    #pragma unroll
    for (int c = 0; c < 24; c++) *(float4*)(&wv[c * 4]) = wr4[c];
  }
  float bl0 = bl[0], bl1 = bl[1], bl2 = bl[2];
  const int* sr = src + b * 360;
  __syncthreads();

  for (int p = wave; p < 91; p += 4){
    int i = 0, rem = p;
    while (rem >= 13 - i){ rem -= 13 - i; i++; }
    int j = i + 1 + rem;
    int base = 12 * i - (i * (i - 1)) / 2;
    int pe = base + (j - i) - 1;
    int eb = 28 + 2 * pe;

    int idxg;
    if (g == 0) idxg = 2 * i;
    else if (g == 1) idxg = 2 * i + 1;
    else if (g == 2) idxg = 2 * j;
    else if (g == 3) idxg = 2 * j + 1;
    else idxg = eb + (g - 4);
    bool zm = !(g >= 4 && j == 13);

    uint4 xv[4];
    #pragma unroll
    for (int c = 0; c < 4; c++) xv[c] = *(uint4*)(&Xs[idxg][sub * 32 + c * 8]);
    const bf16* xa = (const bf16*)xv;
    float a0 = 0.f, a1 = 0.f, a2 = 0.f;
    #pragma unroll
    for (int t = 0; t < 32; t++){
      float f = zm ? __bfloat162float(xa[t]) : 0.0f;
      a0 += f * wv[t * 3 + 0];
      a1 += f * wv[t * 3 + 1];
      a2 += f * wv[t * 3 + 2];
    }
    #pragma unroll
    for (int o = 1; o < 64; o <<= 1){
      a0 += __shfl_xor(a0, o, 64);
      a1 += __shfl_xor(a1, o, 64);
      a2 += __shfl_xor(a2, o, 64);
    }
    if (lane == 0){
      int ti = sr[2 * i], ai = sr[2 * i + 1], tj = sr[2 * j], aj = sr[2 * j + 1];
      bool c1 = (ai == 2) || (aj == 2);
      bool c2 = (tj == 1) || (ai == 1) || (aj == 1);
      bool c3 = (ti == 799) || (tj == 799) || (ai == 0) || (aj == 0);
      bool c4 = false;
      if (j < 13){
        int es = 28 + 4 * pe;
        c4 = (sr[es] == 1) || (sr[es + 1] == 1) || (sr[es + 2] == 1) || (sr[es + 3] == 1);
      }
      bool m1 = c3 || c4, m2 = m1 || c2, m3 = m2 || c1;
      float* op = out + ((size_t)b * 91 + p) * 3;
      op[0] = m1 ? -1.0e9f : (a0 + bl0);
      op[1] = m2 ? -1.0e9f : (a1 + bl1);
      op[2] = m3 ? -1.0e9f : (a2 + bl2);
    }
  }
}

extern "C" void kernel_launch(void* const* d_in, const int* in_sizes, int n_in,
                              void* d_out, int out_size, void* d_ws, size_t ws_size,
                              hipStream_t stream)
{
  const int*   src = (const int*)  d_in[0];
  const float* emb = (const float*)d_in[1];
  const float* wq  = (const float*)d_in[2];  const float* bq = (const float*)d_in[3];
  const float* wk  = (const float*)d_in[4];  const float* bk = (const float*)d_in[5];
  const float* wv  = (const float*)d_in[6];  const float* bv = (const float*)d_in[7];
  const float* wo  = (const float*)d_in[8];  const float* bo = (const float*)d_in[9];
  const float* n1a = (const float*)d_in[10]; const float* n1b = (const float*)d_in[11];
  const float* n2a = (const float*)d_in[12]; const float* n2b = (const float*)d_in[13];
  const float* w1  = (const float*)d_in[14]; const float* b1 = (const float*)d_in[15];
  const float* w2  = (const float*)d_in[16]; const float* b2 = (const float*)d_in[17];
  const float* wl  = (const float*)d_in[18]; const float* bl = (const float*)d_in[19];
  float* out = (float*)d_out;

  if (ws_size < 191365120ull) return;

  char* ws = (char*)d_ws;
  bf16* x   = (bf16*)(ws);                    // [92160][256] bf16
  bf16* xn  = (bf16*)(ws + 47185920ull);      // [92160][256] bf16 (LN1)
  char* R   = ws + 94371840ull;
  bf16* qh   = (bf16*)(R);                    // attn phase
  bf16* kh   = (bf16*)(R + 23592960ull);
  bf16* vth  = (bf16*)(R + 47185920ull);
  bf16* ctxh = (bf16*)(R + 70778880ull);
  uchar* h8  = (uchar*)(R);                   // ffn: [23040][2048] fp8
  uchar* xn8 = (uchar*)(R + 47185920ull);     // ffn: [92160][256] fp8 (LN2)
  char* wC   = ws + 188743680ull;
  bf16* wqT = (bf16*)(wC);
  bf16* wkT = (bf16*)(wC + 131072);
  bf16* wvT = (bf16*)(wC + 262144);
  bf16* woT = (bf16*)(wC + 393216);
  uchar* w1f8T = (uchar*)(wC + 524288);       // [2048][256] fp8
  uchar* w2f8T = (uchar*)(wC + 1048576);      // [256][2048] fp8

  cvt_all<<<1280, 256, 0, stream>>>(wq, wk, wv, wo, w1, w2,
                                    wqT, wkT, wvT, woT, w1f8T, w2f8T);

  embed_ln1<<<23040, 256, 0, stream>>>(src, emb, n1a, n1b, x, xn);

  for (int half = 0; half < 2; half++){
    size_t ro = (size_t)half * 46080;
    const bf16* xnh = xn + ro * 256;
    gemm_bt<4><<<2160, 256, 0, stream>>>(xnh, 256, wqT, 256, nullptr, qh, nullptr,
                                         768, 256, 6, bq, bk, bv);
    attn4<<<512, 512, 0, stream>>>(qh, kh, vth, src + ro, ctxh);
    gemm_bt<3><<<720, 256, 0, stream>>>(ctxh, 256, woT, 256, bo, nullptr, x + ro * 256,
                                        256, 256, 2, nullptr, nullptr, nullptr);
  }

  ln_k8<<<23040, 256, 0, stream>>>(x, n2a, n2b, xn8);

  for (int mc = 0; mc < 4; mc++){
    const uchar* xnc = xn8 + (size_t)mc * 23040 * 256;
    bf16* xc = x + (size_t)mc * 23040 * 256;
    gemm_f8<2><<<2880, 256, 0, stream>>>(xnc, 256, w1f8T, 256, b1, h8, nullptr,
                                         2048, 256, 16);
    gemm_f8<3><<<360, 256, 0, stream>>>(h8, 2048, w2f8T, 2048, b2, nullptr, xc,
                                        256, 2048, 2);
  }

  head_k<<<256, 256, 0, stream>>>(x, src, wl, bl, out);
}

// Round 11
// 829.028 us; speedup vs baseline: 1.1657x; 1.0270x over previous
//
#include <hip/hip_runtime.h>
#include <hip/hip_bf16.h>
#include <math.h>

// ---------------------------------------------------------------------------
// Round 10: XCD-aware block remap in gemm_bt/gemm_f8:
//   bi = (bid & 7) * (grid/8) + (bid >> 3)
// so each XCD (round-robin dispatch) owns a contiguous m-tile range and
// A-tiles are fetched once per XCD instead of once per n-tile-owning XCD
// (R10 QKV FETCH was 71MB vs 24MB ideal). Everything else = R9.
// ws layout 191,365,120 B unchanged.
// ---------------------------------------------------------------------------

using bf16 = __hip_bfloat16;
typedef __attribute__((ext_vector_type(8))) short frag8;
typedef __attribute__((ext_vector_type(4))) float f32x4;
typedef long long i64;
typedef unsigned char uchar;

static __device__ __forceinline__ float wave_sum64(float v){
  #pragma unroll
  for (int o = 32; o >= 1; o >>= 1) v += __shfl_xor(v, o, 64);
  return v;
}

static __device__ __forceinline__ void gl_lds16(const void* g, void* l){
  __builtin_amdgcn_global_load_lds((const __attribute__((address_space(1))) void*)g,
                                   (__attribute__((address_space(3))) void*)l, 16, 0, 0);
}

static __device__ __forceinline__ unsigned pack2(float a, float b){
  union { bf16 h[2]; unsigned u; } u;
  u.h[0] = __float2bfloat16(a); u.h[1] = __float2bfloat16(b);
  return u.u;
}

static __device__ __forceinline__ uchar f2f8(float v){
  return (uchar)(__builtin_amdgcn_cvt_pk_fp8_f32(v, 0.f, 0, false) & 0xff);
}
static __device__ __forceinline__ unsigned pack4_fp8(float a, float b, float c, float d){
  int v = __builtin_amdgcn_cvt_pk_fp8_f32(a, b, 0, false);
  v = __builtin_amdgcn_cvt_pk_fp8_f32(c, d, v, true);
  return (unsigned)v;
}

// merged weight prep: jobs 0-3 bf16 256x256 transposes (wq,wk,wv,wo),
// jobs 4,5: w1 [256][2048] / w2 [2048][256] -> fp8 transposed. 1280 blocks.
__global__ __launch_bounds__(256) void cvt_all(
    const float* s0, const float* s1, const float* s2, const float* s3,
    const float* s4, const float* s5,
    bf16* d0, bf16* d1, bf16* d2, bf16* d3, uchar* d4, uchar* d5)
{
  __shared__ float t[32][33];
  const float* srcs[6] = {s0, s1, s2, s3, s4, s5};
  const int Ks[6] = {256, 256, 256, 256, 256, 2048};
  const int Ns[6] = {256, 256, 256, 256, 2048, 256};
  const int offs[7] = {0, 64, 128, 192, 256, 768, 1280};
  int bid = blockIdx.x, j = 5;
  #pragma unroll
  for (int q = 4; q >= 0; q--) if (bid < offs[q + 1]) j = q;
  int local = bid - offs[j];
  int K = Ks[j], N = Ns[j];
  const float* src = srcs[j];
  int kt = K >> 5;
  int kb = (local % kt) * 32, nb = (local / kt) * 32;
  int tx = threadIdx.x & 31, ty = threadIdx.x >> 5;
  #pragma unroll
  for (int dy = 0; dy < 32; dy += 8)
    t[ty + dy][tx] = src[(size_t)(kb + ty + dy) * N + nb + tx];
  __syncthreads();
  if (j < 4){
    bf16* dst = (j == 0) ? d0 : (j == 1) ? d1 : (j == 2) ? d2 : d3;
    #pragma unroll
    for (int dy = 0; dy < 32; dy += 8)
      dst[(size_t)(nb + ty + dy) * K + kb + tx] = __float2bfloat16(t[tx][ty + dy]);
  } else {
    uchar* dst = (j == 4) ? d4 : d5;
    #pragma unroll
    for (int dy = 0; dy < 32; dy += 8)
      dst[(size_t)(nb + ty + dy) * K + kb + tx] = f2f8(t[tx][ty + dy]);
  }
}

// embed + PE + scale -> x (bf16), LN1 -> xn (bf16). one wave/row, grid 23040.
__global__ __launch_bounds__(256) void embed_ln1(
    const int* __restrict__ src, const float* __restrict__ emb,
    const float* __restrict__ na, const float* __restrict__ nb,
    bf16* __restrict__ x, bf16* __restrict__ xn)
{
  int row  = blockIdx.x * 4 + (threadIdx.x >> 6);
  int lane = threadIdx.x & 63;
  int s = row % 360;
  int tok = src[row];
  float4 v = *(const float4*)(emb + (size_t)tok * 256 + lane * 4);
  float vv[4] = {v.x, v.y, v.z, v.w};
  if (s < 340){
    const float C = (-2.0f / 256.0f) * 13.287712379549449f;
    #pragma unroll
    for (int t = 0; t < 4; t++){
      int c = lane * 4 + t;
      float ang = (float)s * exp2f(C * (float)c);
      float pe = (c & 1) ? cosf(ang) : sinf(ang);
      vv[t] = 16.0f * vv[t] + pe;
    }
  }
  float sum = wave_sum64(vv[0] + vv[1] + vv[2] + vv[3]);
  float mu = sum * (1.0f / 256.0f);
  float d0 = vv[0]-mu, d1 = vv[1]-mu, d2 = vv[2]-mu, d3 = vv[3]-mu;
  float sq = wave_sum64(d0*d0 + d1*d1 + d2*d2 + d3*d3);
  float inv = 1.0f / (sqrtf(sq * (1.0f / 255.0f)) + 1e-6f);
  bf16 xo[4] = { __float2bfloat16(vv[0]), __float2bfloat16(vv[1]),
                 __float2bfloat16(vv[2]), __float2bfloat16(vv[3]) };
  *(uint2*)(x + (size_t)row * 256 + lane * 4) = *(uint2*)xo;
  float4 a4 = *(const float4*)(na + lane * 4);
  float4 b4 = *(const float4*)(nb + lane * 4);
  bf16 o4[4] = { __float2bfloat16(a4.x * d0 * inv + b4.x),
                 __float2bfloat16(a4.y * d1 * inv + b4.y),
                 __float2bfloat16(a4.z * d2 * inv + b4.z),
                 __float2bfloat16(a4.w * d3 * inv + b4.w) };
  *(uint2*)(xn + (size_t)row * 256 + lane * 4) = *(uint2*)o4;
}

// LN2 over bf16 x -> fp8 xn8. one wave per row. grid 23040.
__global__ __launch_bounds__(256) void ln_k8(
    const bf16* __restrict__ x, const float* __restrict__ na,
    const float* __restrict__ nb, uchar* __restrict__ xn8)
{
  int row  = blockIdx.x * 4 + (threadIdx.x >> 6);
  int lane = threadIdx.x & 63;
  uint2 raw = *(const uint2*)(x + (size_t)row * 256 + lane * 4);
  bf16* xr = (bf16*)&raw;
  float v0 = __bfloat162float(xr[0]), v1 = __bfloat162float(xr[1]);
  float v2 = __bfloat162float(xr[2]), v3 = __bfloat162float(xr[3]);
  float sum = wave_sum64(v0 + v1 + v2 + v3);
  float mu = sum * (1.0f / 256.0f);
  float d0 = v0-mu, d1 = v1-mu, d2 = v2-mu, d3 = v3-mu;
  float sq = wave_sum64(d0*d0 + d1*d1 + d2*d2 + d3*d3);
  float inv = 1.0f / (sqrtf(sq * (1.0f / 255.0f)) + 1e-6f);
  float4 a4 = *(const float4*)(na + lane * 4);
  float4 b4 = *(const float4*)(nb + lane * 4);
  unsigned u = pack4_fp8(a4.x * d0 * inv + b4.x, a4.y * d1 * inv + b4.y,
                         a4.z * d2 * inv + b4.z, a4.w * d3 * inv + b4.w);
  *(unsigned*)(xn8 + (size_t)row * 256 + lane * 4) = u;
}

// bf16 GEMM: C = A[M][K] @ Bt[N][K]^T. 128x128 tile, BK=64, swizzled LDS,
// XCD-aware block remap (grid must be divisible by 8).
// MODE 3: bf16 residual in-place: xres[m*256+n] += acc (+bias)
// MODE 4: merged QKV (N=768): region: 0 q-layout, 1 k-layout, 2 v^T
template<int MODE>
__global__ __launch_bounds__(256) void gemm_bt(
    const bf16* __restrict__ A, int lda,
    const bf16* __restrict__ Bt, int ldb,
    const float* __restrict__ bias,
    bf16* __restrict__ outb, bf16* __restrict__ xres,
    int N, int K, int nTiles,
    const float* __restrict__ bq, const float* __restrict__ bk,
    const float* __restrict__ bv)
{
  __shared__ __align__(16) char smem[32768];
  bf16* As = (bf16*)smem;
  bf16* Bs = (bf16*)(smem + 16384);
  bf16 (*Cs)[136] = (bf16 (*)[136])smem;
  int chunk = gridDim.x >> 3;
  int bi = (blockIdx.x & 7) * chunk + (blockIdx.x >> 3);   // XCD-contiguous
  int m0 = (bi / nTiles) * 128, n0 = (bi % nTiles) * 128;
  int tid = threadIdx.x;
  int wave = tid >> 6, lane = tid & 63;
  int wm = (wave >> 1) * 64, wn = (wave & 1) * 64;
  int r = lane & 15, qd = lane >> 4;

  const bf16* ag[4]; const bf16* bg[4]; bf16* la[4]; bf16* lb[4];
  #pragma unroll
  for (int j = 0; j < 4; j++){
    int c = tid + j * 256;
    int row = c >> 3, pl = c & 7;
    int lco = pl ^ (row & 7);
    ag[j] = A  + (size_t)(m0 + row) * lda + lco * 8;
    bg[j] = Bt + (size_t)(n0 + row) * ldb + lco * 8;
    la[j] = As + (size_t)c * 8;
    lb[j] = Bs + (size_t)c * 8;
  }

  f32x4 acc[4][4];
  #pragma unroll
  for (int mt = 0; mt < 4; mt++)
    #pragma unroll
    for (int nt = 0; nt < 4; nt++) acc[mt][nt] = (f32x4){0.f, 0.f, 0.f, 0.f};

  for (int k0 = 0; k0 < K; k0 += 64){
    #pragma unroll
    for (int j = 0; j < 4; j++){ gl_lds16(ag[j], la[j]); gl_lds16(bg[j], lb[j]); }
    #pragma unroll
    for (int j = 0; j < 4; j++){ ag[j] += 64; bg[j] += 64; }
    __syncthreads();
    #pragma unroll
    for (int ph = 0; ph < 2; ph++){
      frag8 af[4], bfr[4];
      #pragma unroll
      for (int t = 0; t < 4; t++){
        int sw = ((ph * 4 + qd) ^ (r & 7)) * 8;
        af[t]  = *(const frag8*)(As + (wm + t * 16 + r) * 64 + sw);
        bfr[t] = *(const frag8*)(Bs + (wn + t * 16 + r) * 64 + sw);
      }
      #pragma unroll
      for (int mt = 0; mt < 4; mt++)
        #pragma unroll
        for (int nt = 0; nt < 4; nt++)
          acc[mt][nt] = __builtin_amdgcn_mfma_f32_16x16x32_bf16(af[mt], bfr[nt], acc[mt][nt], 0, 0, 0);
    }
    __syncthreads();
  }

  const int region = (MODE == 4) ? (n0 >> 8) : 0;
  const float* bb = (MODE == 4) ? (region == 0 ? bq : region == 1 ? bk : bv) : bias;

  #pragma unroll
  for (int half = 0; half < 2; half++){
    if ((wave >> 1) == half){
      #pragma unroll
      for (int mt = 0; mt < 4; mt++)
        #pragma unroll
        for (int nt = 0; nt < 4; nt++)
          #pragma unroll
          for (int i = 0; i < 4; i++){
            int lm = mt * 16 + qd * 4 + i;
            int ln = wn + nt * 16 + r;
            float v = acc[mt][nt][i];
            if (MODE == 3){ if (bb) v += bb[n0 + ln]; }
            else { v += bb[(n0 & 255) + ln]; }
            Cs[lm][ln] = __float2bfloat16(v);
          }
    }
    __syncthreads();
    int mbase = m0 + half * 64;
    if (MODE == 3){
      int lr = tid >> 2, seg = tid & 3;
      bf16* op = xres + (size_t)(mbase + lr) * 256 + n0 + seg * 32;
      #pragma unroll
      for (int j = 0; j < 4; j++){
        uint4 cv = *(uint4*)(&Cs[lr][seg * 32 + j * 8]);
        uint4 xv = *(uint4*)(op + j * 8);
        bf16* ca = (bf16*)&cv; bf16* xa = (bf16*)&xv;
        bf16 o8[8];
        #pragma unroll
        for (int t = 0; t < 8; t++)
          o8[t] = __float2bfloat16(__bfloat162float(ca[t]) + __bfloat162float(xa[t]));
        *(uint4*)(op + j * 8) = *(uint4*)o8;
      }
    } else {
      if (region < 2){
        int lr = tid >> 2, seg = tid & 3;
        int m = mbase + lr;
        int b_ = m / 360, s = m - b_ * 360;
        int nnl = (n0 & 255) + seg * 32;
        int h = nnl >> 6, dk = nnl & 63;
        size_t roff = (region == 1) ? 11796480ull : 0ull;
        bf16* op = outb + roff + (((size_t)(b_ * 4 + h) * 360 + s) << 6) + dk;
        #pragma unroll
        for (int j = 0; j < 4; j++)
          *(uint4*)(op + j * 8) = *(uint4*)(&Cs[lr][seg * 32 + j * 8]);
      } else {
        int nn = tid >> 1;
        int nnl = (n0 & 255) + nn;
        int h = nnl >> 6, dk = nnl & 63;
        int msub = (tid & 1) * 32;
        #pragma unroll
        for (int j0 = 0; j0 < 32; j0 += 8){
          int m = mbase + msub + j0;
          int b_ = m / 360, s = m - b_ * 360;
          bf16 tmp[8];
          #pragma unroll
          for (int t = 0; t < 8; t++) tmp[t] = Cs[msub + j0 + t][nn];
          *(uint4*)(outb + 23592960ull + ((size_t)((b_ * 4 + h) * 64 + dk)) * 360 + s) =
              *(uint4*)tmp;
        }
      }
    }
    __syncthreads();
  }
}

// fp8 GEMM: C = A[M][K](e4m3) @ Bt[N][K]^T(e4m3). 128x128 tile, BK=64,
// 16B-granule XOR swizzle, XCD-aware block remap.
// MODE 2: relu -> fp8 row-major [M][N]
// MODE 3: bf16 residual in-place += acc (+bias)
template<int MODE>
__global__ __launch_bounds__(256) void gemm_f8(
    const uchar* __restrict__ A, int lda,
    const uchar* __restrict__ Bt, int ldb,
    const float* __restrict__ bias,
    uchar* __restrict__ out8, bf16* __restrict__ xres,
    int N, int K, int nTiles)
{
  __shared__ __align__(16) char smem[17408];   // As 8K | Bs 8K ; Cs/Cs8 alias
  uchar* As = (uchar*)smem;
  uchar* Bs = (uchar*)(smem + 8192);
  bf16 (*Cs)[136] = (bf16 (*)[136])smem;
  uchar (*Cs8)[144] = (uchar (*)[144])smem;
  int chunk = gridDim.x >> 3;
  int bi = (blockIdx.x & 7) * chunk + (blockIdx.x >> 3);   // XCD-contiguous
  int m0 = (bi / nTiles) * 128, n0 = (bi % nTiles) * 128;
  int tid = threadIdx.x;
  int wave = tid >> 6, lane = tid & 63;
  int wm = (wave >> 1) * 64, wn = (wave & 1) * 64;
  int r = lane & 15, qd = lane >> 4;

  const uchar* ag[2]; const uchar* bg[2]; uchar* la[2]; uchar* lb[2];
  #pragma unroll
  for (int j = 0; j < 2; j++){
    int c = tid + j * 256;
    int row = c >> 2, pp = c & 3;
    int lco = pp ^ (row & 3);
    ag[j] = A  + (size_t)(m0 + row) * lda + lco * 16;
    bg[j] = Bt + (size_t)(n0 + row) * ldb + lco * 16;
    la[j] = As + (size_t)c * 16;
    lb[j] = Bs + (size_t)c * 16;
  }

  f32x4 acc[4][4];
  #pragma unroll
  for (int mt = 0; mt < 4; mt++)
    #pragma unroll
    for (int nt = 0; nt < 4; nt++) acc[mt][nt] = (f32x4){0.f, 0.f, 0.f, 0.f};

  for (int k0 = 0; k0 < K; k0 += 64){
    #pragma unroll
    for (int j = 0; j < 2; j++){ gl_lds16(ag[j], la[j]); gl_lds16(bg[j], lb[j]); }
    #pragma unroll
    for (int j = 0; j < 2; j++){ ag[j] += 64; bg[j] += 64; }
    __syncthreads();
    #pragma unroll
    for (int ph = 0; ph < 2; ph++){
      int l16 = ph * 2 + (qd >> 1);
      int woff = (qd & 1) * 8;
      i64 af[4], bfr[4];
      #pragma unroll
      for (int t = 0; t < 4; t++){
        int swA = ((l16 ^ (r & 3)) * 16) + woff;
        af[t]  = *(const i64*)(As + (wm + t * 16 + r) * 64 + swA);
        bfr[t] = *(const i64*)(Bs + (wn + t * 16 + r) * 64 + swA);
      }
      #pragma unroll
      for (int mt = 0; mt < 4; mt++)
        #pragma unroll
        for (int nt = 0; nt < 4; nt++)
          acc[mt][nt] = __builtin_amdgcn_mfma_f32_16x16x32_fp8_fp8(af[mt], bfr[nt], acc[mt][nt], 0, 0, 0);
    }
    __syncthreads();
  }

  #pragma unroll
  for (int half = 0; half < 2; half++){
    if ((wave >> 1) == half){
      #pragma unroll
      for (int mt = 0; mt < 4; mt++)
        #pragma unroll
        for (int nt = 0; nt < 4; nt++)
          #pragma unroll
          for (int i = 0; i < 4; i++){
            int lm = mt * 16 + qd * 4 + i;
            int ln = wn + nt * 16 + r;
            float v = acc[mt][nt][i] + bias[n0 + ln];
            if (MODE == 2){
              Cs8[lm][ln] = f2f8(fmaxf(v, 0.0f));
            } else {
              Cs[lm][ln] = __float2bfloat16(v);
            }
          }
    }
    __syncthreads();
    int mbase = m0 + half * 64;
    if (MODE == 2){
      int lr = tid >> 2, seg = tid & 3;
      uchar* op = out8 + (size_t)(mbase + lr) * N + n0 + seg * 32;
      #pragma unroll
      for (int j = 0; j < 2; j++)
        *(uint4*)(op + j * 16) = *(uint4*)(&Cs8[lr][seg * 32 + j * 16]);
    } else {
      int lr = tid >> 2, seg = tid & 3;
      bf16* op = xres + (size_t)(mbase + lr) * 256 + n0 + seg * 32;
      #pragma unroll
      for (int j = 0; j < 4; j++){
        uint4 cv = *(uint4*)(&Cs[lr][seg * 32 + j * 8]);
        uint4 xv = *(uint4*)(op + j * 8);
        bf16* ca = (bf16*)&cv; bf16* xa = (bf16*)&xv;
        bf16 o8[8];
        #pragma unroll
        for (int t = 0; t < 8; t++)
          o8[t] = __float2bfloat16(__bfloat162float(ca[t]) + __bfloat162float(xa[t]));
        *(uint4*)(op + j * 8) = *(uint4*)o8;
      }
    }
    __syncthreads();
  }
}

// attn4: one block per (b_local,h), 512 thr / 8 waves, 3 q-tiles/wave,
// single-pass softmax (scores O(1); pad queries s=0 -> uniform). K LDS-resident.
__global__ __launch_bounds__(512) void attn4(
    const bf16* __restrict__ q, const bf16* __restrict__ kk, const bf16* __restrict__ vt,
    const int* __restrict__ src, bf16* __restrict__ ctx)
{
  __shared__ bf16 Ks[360][72];
  __shared__ bf16 Pb[8][16][48];
  int bh = blockIdx.x;
  int b = bh >> 2, h = bh & 3;
  int wave = threadIdx.x >> 6, lane = threadIdx.x & 63;
  int r = lane & 15, qd = lane >> 4;
  const bf16* qb = q  + (size_t)bh * 360 * 64;
  const bf16* kb = kk + (size_t)bh * 360 * 64;
  const bf16* vb = vt + (size_t)bh * 64 * 360;
  const int* srow = src + b * 360;

  for (int c = threadIdx.x; c < 2880; c += 512){
    int row = c >> 3, g = c & 7;
    *(uint4*)(&Ks[row][g * 8]) = *(const uint4*)(kb + row * 64 + g * 8);
  }
  __syncthreads();

  frag8 qa0[3], qa1[3];
  bool qp[3];
  float lsum[3];
  f32x4 accO[3][4];
  #pragma unroll
  for (int tl = 0; tl < 3; tl++){
    int qt = wave * 3 + tl;
    int qg = qt * 16 + r;
    int qrow = qg > 359 ? 359 : qg;
    qa0[tl] = *(const frag8*)(qb + qrow * 64 + qd * 8);
    qa1[tl] = *(const frag8*)(qb + qrow * 64 + 32 + qd * 8);
    qp[tl] = (qg < 360) && (srow[qg] == 799);
    lsum[tl] = 0.f;
    #pragma unroll
    for (int dt = 0; dt < 4; dt++) accO[tl][dt] = (f32x4){0.f, 0.f, 0.f, 0.f};
  }

  for (int kc = 0; kc < 12; kc++){
    int krow0 = kc * 32 + r;      if (krow0 > 359) krow0 = 359;
    int krow1 = kc * 32 + 16 + r; if (krow1 > 359) krow1 = 359;
    frag8 kf00 = *(const frag8*)(&Ks[krow0][qd * 8]);
    frag8 kf01 = *(const frag8*)(&Ks[krow0][32 + qd * 8]);
    frag8 kf10 = *(const frag8*)(&Ks[krow1][qd * 8]);
    frag8 kf11 = *(const frag8*)(&Ks[krow1][32 + qd * 8]);
    frag8 vf[4];
    #pragma unroll
    for (int dt = 0; dt < 4; dt++)
      vf[dt] = *(const frag8*)(vb + (size_t)(dt * 16 + r) * 360 + kc * 32 + qd * 8);

    #pragma unroll
    for (int tl = 0; tl < 3; tl++){
      f32x4 z0 = {0.f, 0.f, 0.f, 0.f}, z1 = {0.f, 0.f, 0.f, 0.f};
      z0 = __builtin_amdgcn_mfma_f32_16x16x32_bf16(kf00, qa0[tl], z0, 0, 0, 0);
      z0 = __builtin_amdgcn_mfma_f32_16x16x32_bf16(kf01, qa1[tl], z0, 0, 0, 0);
      z1 = __builtin_amdgcn_mfma_f32_16x16x32_bf16(kf10, qa0[tl], z1, 0, 0, 0);
      z1 = __builtin_amdgcn_mfma_f32_16x16x32_bf16(kf11, qa1[tl], z1, 0, 0, 0);
      float p0[4], p1[4];
      #pragma unroll
      for (int i = 0; i < 4; i++){
        int key0 = kc * 32 + qd * 4 + i;
        int key1 = key0 + 16;
        float s0 = z0[i] * 0.125f, s1 = z1[i] * 0.125f;
        if (qp[tl]){ s0 = 0.0f; s1 = 0.0f; }
        p0[i] = (key0 < 360) ? __expf(s0) : 0.0f;
        p1[i] = (key1 < 360) ? __expf(s1) : 0.0f;
        lsum[tl] += p0[i] + p1[i];
      }
      *(uint2*)(&Pb[wave][r][qd * 4])      = make_uint2(pack2(p0[0], p0[1]), pack2(p0[2], p0[3]));
      *(uint2*)(&Pb[wave][r][16 + qd * 4]) = make_uint2(pack2(p1[0], p1[1]), pack2(p1[2], p1[3]));
      asm volatile("s_waitcnt lgkmcnt(0)" ::: "memory");
      frag8 pa = *(const frag8*)(&Pb[wave][r][qd * 8]);
      #pragma unroll
      for (int dt = 0; dt < 4; dt++)
        accO[tl][dt] = __builtin_amdgcn_mfma_f32_16x16x32_bf16(pa, vf[dt], accO[tl][dt], 0, 0, 0);
      asm volatile("s_waitcnt lgkmcnt(0)" ::: "memory");
    }
  }

  #pragma unroll
  for (int tl = 0; tl < 3; tl++){
    int qt = wave * 3 + tl;
    float ls = lsum[tl];
    ls += __shfl_xor(ls, 16, 64);
    ls += __shfl_xor(ls, 32, 64);
    float invl = 1.0f / ls;
    #pragma unroll
    for (int i = 0; i < 4; i++){
      float inv_i = __shfl(invl, qd * 4 + i, 64);
      int qglob = qt * 16 + qd * 4 + i;
      if (qglob < 360){
        #pragma unroll
        for (int dt = 0; dt < 4; dt++)
          ctx[((size_t)(b * 360 + qglob)) * 256 + h * 64 + dt * 16 + r] =
              __float2bfloat16(accO[tl][dt][i] * inv_i);
      }
    }
  }
}

// head: one block per batch (grid 256, 4 waves). x rows 0..191 staged in LDS,
// wl register-resident per lane, waves sweep pairs p = wave, wave+4, ...
__global__ __launch_bounds__(256) void head_k(
    const bf16* __restrict__ x, const int* __restrict__ src,
    const float* __restrict__ wl, const float* __restrict__ bl,
    float* __restrict__ out)
{
  __shared__ bf16 Xs[192][264];
  int b = blockIdx.x;
  int tid = threadIdx.x;
  int wave = tid >> 6, lane = tid & 63;
  int g = lane >> 3, sub = lane & 7;

  const bf16* xb = x + (size_t)b * 360 * 256;
  for (int it = 0; it < 24; it++){
    int idx = tid + it * 256;
    int row = idx >> 5, col = idx & 31;
    *(uint4*)(&Xs[row][col * 8]) = *(const uint4*)(xb + row * 256 + col * 8);
  }

  float wv[96];
  {
    const float4* wr4 = (const float4*)(wl + (size_t)(g * 256 + sub * 32) * 3);
    #pragma unroll
    for (int c = 0; c < 24; c++) *(float4*)(&wv[c * 4]) = wr4[c];
  }
  float bl0 = bl[0], bl1 = bl[1], bl2 = bl[2];
  const int* sr = src + b * 360;
  __syncthreads();

  for (int p = wave; p < 91; p += 4){
    int i = 0, rem = p;
    while (rem >= 13 - i){ rem -= 13 - i; i++; }
    int j = i + 1 + rem;
    int base = 12 * i - (i * (i - 1)) / 2;
    int pe = base + (j - i) - 1;
    int eb = 28 + 2 * pe;

    int idxg;
    if (g == 0) idxg = 2 * i;
    else if (g == 1) idxg = 2 * i + 1;
    else if (g == 2) idxg = 2 * j;
    else if (g == 3) idxg = 2 * j + 1;
    else idxg = eb + (g - 4);
    bool zm = !(g >= 4 && j == 13);

    uint4 xv[4];
    #pragma unroll
    for (int c = 0; c < 4; c++) xv[c] = *(uint4*)(&Xs[idxg][sub * 32 + c * 8]);
    const bf16* xa = (const bf16*)xv;
    float a0 = 0.f, a1 = 0.f, a2 = 0.f;
    #pragma unroll
    for (int t = 0; t < 32; t++){
      float f = zm ? __bfloat162float(xa[t]) : 0.0f;
      a0 += f * wv[t * 3 + 0];
      a1 += f * wv[t * 3 + 1];
      a2 += f * wv[t * 3 + 2];
    }
    #pragma unroll
    for (int o = 1; o < 64; o <<= 1){
      a0 += __shfl_xor(a0, o, 64);
      a1 += __shfl_xor(a1, o, 64);
      a2 += __shfl_xor(a2, o, 64);
    }
    if (lane == 0){
      int ti = sr[2 * i], ai = sr[2 * i + 1], tj = sr[2 * j], aj = sr[2 * j + 1];
      bool c1 = (ai == 2) || (aj == 2);
      bool c2 = (tj == 1) || (ai == 1) || (aj == 1);
      bool c3 = (ti == 799) || (tj == 799) || (ai == 0) || (aj == 0);
      bool c4 = false;
      if (j < 13){
        int es = 28 + 4 * pe;
        c4 = (sr[es] == 1) || (sr[es + 1] == 1) || (sr[es + 2] == 1) || (sr[es + 3] == 1);
      }
      bool m1 = c3 || c4, m2 = m1 || c2, m3 = m2 || c1;
      float* op = out + ((size_t)b * 91 + p) * 3;
      op[0] = m1 ? -1.0e9f : (a0 + bl0);
      op[1] = m2 ? -1.0e9f : (a1 + bl1);
      op[2] = m3 ? -1.0e9f : (a2 + bl2);
    }
  }
}

extern "C" void kernel_launch(void* const* d_in, const int* in_sizes, int n_in,
                              void* d_out, int out_size, void* d_ws, size_t ws_size,
                              hipStream_t stream)
{
  const int*   src = (const int*)  d_in[0];
  const float* emb = (const float*)d_in[1];
  const float* wq  = (const float*)d_in[2];  const float* bq = (const float*)d_in[3];
  const float* wk  = (const float*)d_in[4];  const float* bk = (const float*)d_in[5];
  const float* wv  = (const float*)d_in[6];  const float* bv = (const float*)d_in[7];
  const float* wo  = (const float*)d_in[8];  const float* bo = (const float*)d_in[9];
  const float* n1a = (const float*)d_in[10]; const float* n1b = (const float*)d_in[11];
  const float* n2a = (const float*)d_in[12]; const float* n2b = (const float*)d_in[13];
  const float* w1  = (const float*)d_in[14]; const float* b1 = (const float*)d_in[15];
  const float* w2  = (const float*)d_in[16]; const float* b2 = (const float*)d_in[17];
  const float* wl  = (const float*)d_in[18]; const float* bl = (const float*)d_in[19];
  float* out = (float*)d_out;

  if (ws_size < 191365120ull) return;

  char* ws = (char*)d_ws;
  bf16* x   = (bf16*)(ws);                    // [92160][256] bf16
  bf16* xn  = (bf16*)(ws + 47185920ull);      // [92160][256] bf16 (LN1)
  char* R   = ws + 94371840ull;
  bf16* qh   = (bf16*)(R);                    // attn phase
  bf16* kh   = (bf16*)(R + 23592960ull);
  bf16* vth  = (bf16*)(R + 47185920ull);
  bf16* ctxh = (bf16*)(R + 70778880ull);
  uchar* h8  = (uchar*)(R);                   // ffn: [23040][2048] fp8
  uchar* xn8 = (uchar*)(R + 47185920ull);     // ffn: [92160][256] fp8 (LN2)
  char* wC   = ws + 188743680ull;
  bf16* wqT = (bf16*)(wC);
  bf16* wkT = (bf16*)(wC + 131072);
  bf16* wvT = (bf16*)(wC + 262144);
  bf16* woT = (bf16*)(wC + 393216);
  uchar* w1f8T = (uchar*)(wC + 524288);       // [2048][256] fp8
  uchar* w2f8T = (uchar*)(wC + 1048576);      // [256][2048] fp8

  cvt_all<<<1280, 256, 0, stream>>>(wq, wk, wv, wo, w1, w2,
                                    wqT, wkT, wvT, woT, w1f8T, w2f8T);

  embed_ln1<<<23040, 256, 0, stream>>>(src, emb, n1a, n1b, x, xn);

  for (int half = 0; half < 2; half++){
    size_t ro = (size_t)half * 46080;
    const bf16* xnh = xn + ro * 256;
    gemm_bt<4><<<2160, 256, 0, stream>>>(xnh, 256, wqT, 256, nullptr, qh, nullptr,
                                         768, 256, 6, bq, bk, bv);
    attn4<<<512, 512, 0, stream>>>(qh, kh, vth, src + ro, ctxh);
    gemm_bt<3><<<720, 256, 0, stream>>>(ctxh, 256, woT, 256, bo, nullptr, x + ro * 256,
                                        256, 256, 2, nullptr, nullptr, nullptr);
  }

  ln_k8<<<23040, 256, 0, stream>>>(x, n2a, n2b, xn8);

  for (int mc = 0; mc < 4; mc++){
    const uchar* xnc = xn8 + (size_t)mc * 23040 * 256;
    bf16* xc = x + (size_t)mc * 23040 * 256;
    gemm_f8<2><<<2880, 256, 0, stream>>>(xnc, 256, w1f8T, 256, b1, h8, nullptr,
                                         2048, 256, 16);
    gemm_f8<3><<<360, 256, 0, stream>>>(h8, 2048, w2f8T, 2048, b2, nullptr, xc,
                                        256, 2048, 2);
  }

  head_k<<<256, 256, 0, stream>>>(x, src, wl, bl, out);
}

// Round 12
// 786.612 us; speedup vs baseline: 1.2285x; 1.0539x over previous
//
#include <hip/hip_runtime.h>
#include <hip/hip_bf16.h>
#include <math.h>

// ---------------------------------------------------------------------------
// Round 11: fp8 GEMM swizzle key fix. R11 counters: FETCH collapsed 47->5MB
// (XCD remap correct) but gemm_f8 SQ_LDS_BANK_CONFLICT=9.0M: key r&3 makes
// lanes r,r+4,r+8,r+12 share a bank-pair (64B rows = 16 banks) -> 4-way.
// New key (r>>1)&3: (r&1,(r>>1)&3)=r&7 -> 8 bank groups / 16 lanes = 2-way
// (free per m136). Staging + read sides changed together (XOR self-inverse,
// numerics identical). Everything else = R11.
// ws layout 191,365,120 B unchanged.
// ---------------------------------------------------------------------------

using bf16 = __hip_bfloat16;
typedef __attribute__((ext_vector_type(8))) short frag8;
typedef __attribute__((ext_vector_type(4))) float f32x4;
typedef long long i64;
typedef unsigned char uchar;

static __device__ __forceinline__ float wave_sum64(float v){
  #pragma unroll
  for (int o = 32; o >= 1; o >>= 1) v += __shfl_xor(v, o, 64);
  return v;
}

static __device__ __forceinline__ void gl_lds16(const void* g, void* l){
  __builtin_amdgcn_global_load_lds((const __attribute__((address_space(1))) void*)g,
                                   (__attribute__((address_space(3))) void*)l, 16, 0, 0);
}

static __device__ __forceinline__ unsigned pack2(float a, float b){
  union { bf16 h[2]; unsigned u; } u;
  u.h[0] = __float2bfloat16(a); u.h[1] = __float2bfloat16(b);
  return u.u;
}

static __device__ __forceinline__ uchar f2f8(float v){
  return (uchar)(__builtin_amdgcn_cvt_pk_fp8_f32(v, 0.f, 0, false) & 0xff);
}
static __device__ __forceinline__ unsigned pack4_fp8(float a, float b, float c, float d){
  int v = __builtin_amdgcn_cvt_pk_fp8_f32(a, b, 0, false);
  v = __builtin_amdgcn_cvt_pk_fp8_f32(c, d, v, true);
  return (unsigned)v;
}

// merged weight prep: jobs 0-3 bf16 256x256 transposes (wq,wk,wv,wo),
// jobs 4,5: w1 [256][2048] / w2 [2048][256] -> fp8 transposed. 1280 blocks.
__global__ __launch_bounds__(256) void cvt_all(
    const float* s0, const float* s1, const float* s2, const float* s3,
    const float* s4, const float* s5,
    bf16* d0, bf16* d1, bf16* d2, bf16* d3, uchar* d4, uchar* d5)
{
  __shared__ float t[32][33];
  const float* srcs[6] = {s0, s1, s2, s3, s4, s5};
  const int Ks[6] = {256, 256, 256, 256, 256, 2048};
  const int Ns[6] = {256, 256, 256, 256, 2048, 256};
  const int offs[7] = {0, 64, 128, 192, 256, 768, 1280};
  int bid = blockIdx.x, j = 5;
  #pragma unroll
  for (int q = 4; q >= 0; q--) if (bid < offs[q + 1]) j = q;
  int local = bid - offs[j];
  int K = Ks[j], N = Ns[j];
  const float* src = srcs[j];
  int kt = K >> 5;
  int kb = (local % kt) * 32, nb = (local / kt) * 32;
  int tx = threadIdx.x & 31, ty = threadIdx.x >> 5;
  #pragma unroll
  for (int dy = 0; dy < 32; dy += 8)
    t[ty + dy][tx] = src[(size_t)(kb + ty + dy) * N + nb + tx];
  __syncthreads();
  if (j < 4){
    bf16* dst = (j == 0) ? d0 : (j == 1) ? d1 : (j == 2) ? d2 : d3;
    #pragma unroll
    for (int dy = 0; dy < 32; dy += 8)
      dst[(size_t)(nb + ty + dy) * K + kb + tx] = __float2bfloat16(t[tx][ty + dy]);
  } else {
    uchar* dst = (j == 4) ? d4 : d5;
    #pragma unroll
    for (int dy = 0; dy < 32; dy += 8)
      dst[(size_t)(nb + ty + dy) * K + kb + tx] = f2f8(t[tx][ty + dy]);
  }
}

// embed + PE + scale -> x (bf16), LN1 -> xn (bf16). one wave/row, grid 23040.
__global__ __launch_bounds__(256) void embed_ln1(
    const int* __restrict__ src, const float* __restrict__ emb,
    const float* __restrict__ na, const float* __restrict__ nb,
    bf16* __restrict__ x, bf16* __restrict__ xn)
{
  int row  = blockIdx.x * 4 + (threadIdx.x >> 6);
  int lane = threadIdx.x & 63;
  int s = row % 360;
  int tok = src[row];
  float4 v = *(const float4*)(emb + (size_t)tok * 256 + lane * 4);
  float vv[4] = {v.x, v.y, v.z, v.w};
  if (s < 340){
    const float C = (-2.0f / 256.0f) * 13.287712379549449f;
    #pragma unroll
    for (int t = 0; t < 4; t++){
      int c = lane * 4 + t;
      float ang = (float)s * exp2f(C * (float)c);
      float pe = (c & 1) ? cosf(ang) : sinf(ang);
      vv[t] = 16.0f * vv[t] + pe;
    }
  }
  float sum = wave_sum64(vv[0] + vv[1] + vv[2] + vv[3]);
  float mu = sum * (1.0f / 256.0f);
  float d0 = vv[0]-mu, d1 = vv[1]-mu, d2 = vv[2]-mu, d3 = vv[3]-mu;
  float sq = wave_sum64(d0*d0 + d1*d1 + d2*d2 + d3*d3);
  float inv = 1.0f / (sqrtf(sq * (1.0f / 255.0f)) + 1e-6f);
  bf16 xo[4] = { __float2bfloat16(vv[0]), __float2bfloat16(vv[1]),
                 __float2bfloat16(vv[2]), __float2bfloat16(vv[3]) };
  *(uint2*)(x + (size_t)row * 256 + lane * 4) = *(uint2*)xo;
  float4 a4 = *(const float4*)(na + lane * 4);
  float4 b4 = *(const float4*)(nb + lane * 4);
  bf16 o4[4] = { __float2bfloat16(a4.x * d0 * inv + b4.x),
                 __float2bfloat16(a4.y * d1 * inv + b4.y),
                 __float2bfloat16(a4.z * d2 * inv + b4.z),
                 __float2bfloat16(a4.w * d3 * inv + b4.w) };
  *(uint2*)(xn + (size_t)row * 256 + lane * 4) = *(uint2*)o4;
}

// LN2 over bf16 x -> fp8 xn8. one wave per row. grid 23040.
__global__ __launch_bounds__(256) void ln_k8(
    const bf16* __restrict__ x, const float* __restrict__ na,
    const float* __restrict__ nb, uchar* __restrict__ xn8)
{
  int row  = blockIdx.x * 4 + (threadIdx.x >> 6);
  int lane = threadIdx.x & 63;
  uint2 raw = *(const uint2*)(x + (size_t)row * 256 + lane * 4);
  bf16* xr = (bf16*)&raw;
  float v0 = __bfloat162float(xr[0]), v1 = __bfloat162float(xr[1]);
  float v2 = __bfloat162float(xr[2]), v3 = __bfloat162float(xr[3]);
  float sum = wave_sum64(v0 + v1 + v2 + v3);
  float mu = sum * (1.0f / 256.0f);
  float d0 = v0-mu, d1 = v1-mu, d2 = v2-mu, d3 = v3-mu;
  float sq = wave_sum64(d0*d0 + d1*d1 + d2*d2 + d3*d3);
  float inv = 1.0f / (sqrtf(sq * (1.0f / 255.0f)) + 1e-6f);
  float4 a4 = *(const float4*)(na + lane * 4);
  float4 b4 = *(const float4*)(nb + lane * 4);
  unsigned u = pack4_fp8(a4.x * d0 * inv + b4.x, a4.y * d1 * inv + b4.y,
                         a4.z * d2 * inv + b4.z, a4.w * d3 * inv + b4.w);
  *(unsigned*)(xn8 + (size_t)row * 256 + lane * 4) = u;
}

// bf16 GEMM: C = A[M][K] @ Bt[N][K]^T. 128x128 tile, BK=64, swizzled LDS,
// XCD-aware block remap (grid must be divisible by 8).
// MODE 3: bf16 residual in-place: xres[m*256+n] += acc (+bias)
// MODE 4: merged QKV (N=768): region: 0 q-layout, 1 k-layout, 2 v^T
template<int MODE>
__global__ __launch_bounds__(256) void gemm_bt(
    const bf16* __restrict__ A, int lda,
    const bf16* __restrict__ Bt, int ldb,
    const float* __restrict__ bias,
    bf16* __restrict__ outb, bf16* __restrict__ xres,
    int N, int K, int nTiles,
    const float* __restrict__ bq, const float* __restrict__ bk,
    const float* __restrict__ bv)
{
  __shared__ __align__(16) char smem[32768];
  bf16* As = (bf16*)smem;
  bf16* Bs = (bf16*)(smem + 16384);
  bf16 (*Cs)[136] = (bf16 (*)[136])smem;
  int chunk = gridDim.x >> 3;
  int bi = (blockIdx.x & 7) * chunk + (blockIdx.x >> 3);   // XCD-contiguous
  int m0 = (bi / nTiles) * 128, n0 = (bi % nTiles) * 128;
  int tid = threadIdx.x;
  int wave = tid >> 6, lane = tid & 63;
  int wm = (wave >> 1) * 64, wn = (wave & 1) * 64;
  int r = lane & 15, qd = lane >> 4;

  const bf16* ag[4]; const bf16* bg[4]; bf16* la[4]; bf16* lb[4];
  #pragma unroll
  for (int j = 0; j < 4; j++){
    int c = tid + j * 256;
    int row = c >> 3, pl = c & 7;
    int lco = pl ^ (row & 7);
    ag[j] = A  + (size_t)(m0 + row) * lda + lco * 8;
    bg[j] = Bt + (size_t)(n0 + row) * ldb + lco * 8;
    la[j] = As + (size_t)c * 8;
    lb[j] = Bs + (size_t)c * 8;
  }

  f32x4 acc[4][4];
  #pragma unroll
  for (int mt = 0; mt < 4; mt++)
    #pragma unroll
    for (int nt = 0; nt < 4; nt++) acc[mt][nt] = (f32x4){0.f, 0.f, 0.f, 0.f};

  for (int k0 = 0; k0 < K; k0 += 64){
    #pragma unroll
    for (int j = 0; j < 4; j++){ gl_lds16(ag[j], la[j]); gl_lds16(bg[j], lb[j]); }
    #pragma unroll
    for (int j = 0; j < 4; j++){ ag[j] += 64; bg[j] += 64; }
    __syncthreads();
    #pragma unroll
    for (int ph = 0; ph < 2; ph++){
      frag8 af[4], bfr[4];
      #pragma unroll
      for (int t = 0; t < 4; t++){
        int sw = ((ph * 4 + qd) ^ (r & 7)) * 8;
        af[t]  = *(const frag8*)(As + (wm + t * 16 + r) * 64 + sw);
        bfr[t] = *(const frag8*)(Bs + (wn + t * 16 + r) * 64 + sw);
      }
      #pragma unroll
      for (int mt = 0; mt < 4; mt++)
        #pragma unroll
        for (int nt = 0; nt < 4; nt++)
          acc[mt][nt] = __builtin_amdgcn_mfma_f32_16x16x32_bf16(af[mt], bfr[nt], acc[mt][nt], 0, 0, 0);
    }
    __syncthreads();
  }

  const int region = (MODE == 4) ? (n0 >> 8) : 0;
  const float* bb = (MODE == 4) ? (region == 0 ? bq : region == 1 ? bk : bv) : bias;

  #pragma unroll
  for (int half = 0; half < 2; half++){
    if ((wave >> 1) == half){
      #pragma unroll
      for (int mt = 0; mt < 4; mt++)
        #pragma unroll
        for (int nt = 0; nt < 4; nt++)
          #pragma unroll
          for (int i = 0; i < 4; i++){
            int lm = mt * 16 + qd * 4 + i;
            int ln = wn + nt * 16 + r;
            float v = acc[mt][nt][i];
            if (MODE == 3){ if (bb) v += bb[n0 + ln]; }
            else { v += bb[(n0 & 255) + ln]; }
            Cs[lm][ln] = __float2bfloat16(v);
          }
    }
    __syncthreads();
    int mbase = m0 + half * 64;
    if (MODE == 3){
      int lr = tid >> 2, seg = tid & 3;
      bf16* op = xres + (size_t)(mbase + lr) * 256 + n0 + seg * 32;
      #pragma unroll
      for (int j = 0; j < 4; j++){
        uint4 cv = *(uint4*)(&Cs[lr][seg * 32 + j * 8]);
        uint4 xv = *(uint4*)(op + j * 8);
        bf16* ca = (bf16*)&cv; bf16* xa = (bf16*)&xv;
        bf16 o8[8];
        #pragma unroll
        for (int t = 0; t < 8; t++)
          o8[t] = __float2bfloat16(__bfloat162float(ca[t]) + __bfloat162float(xa[t]));
        *(uint4*)(op + j * 8) = *(uint4*)o8;
      }
    } else {
      if (region < 2){
        int lr = tid >> 2, seg = tid & 3;
        int m = mbase + lr;
        int b_ = m / 360, s = m - b_ * 360;
        int nnl = (n0 & 255) + seg * 32;
        int h = nnl >> 6, dk = nnl & 63;
        size_t roff = (region == 1) ? 11796480ull : 0ull;
        bf16* op = outb + roff + (((size_t)(b_ * 4 + h) * 360 + s) << 6) + dk;
        #pragma unroll
        for (int j = 0; j < 4; j++)
          *(uint4*)(op + j * 8) = *(uint4*)(&Cs[lr][seg * 32 + j * 8]);
      } else {
        int nn = tid >> 1;
        int nnl = (n0 & 255) + nn;
        int h = nnl >> 6, dk = nnl & 63;
        int msub = (tid & 1) * 32;
        #pragma unroll
        for (int j0 = 0; j0 < 32; j0 += 8){
          int m = mbase + msub + j0;
          int b_ = m / 360, s = m - b_ * 360;
          bf16 tmp[8];
          #pragma unroll
          for (int t = 0; t < 8; t++) tmp[t] = Cs[msub + j0 + t][nn];
          *(uint4*)(outb + 23592960ull + ((size_t)((b_ * 4 + h) * 64 + dk)) * 360 + s) =
              *(uint4*)tmp;
        }
      }
    }
    __syncthreads();
  }
}

// fp8 GEMM: C = A[M][K](e4m3) @ Bt[N][K]^T(e4m3). 128x128 tile, BK=64,
// 16B-granule XOR swizzle key (row>>1)&3, XCD-aware block remap.
// MODE 2: relu -> fp8 row-major [M][N]
// MODE 3: bf16 residual in-place += acc (+bias)
template<int MODE>
__global__ __launch_bounds__(256) void gemm_f8(
    const uchar* __restrict__ A, int lda,
    const uchar* __restrict__ Bt, int ldb,
    const float* __restrict__ bias,
    uchar* __restrict__ out8, bf16* __restrict__ xres,
    int N, int K, int nTiles)
{
  __shared__ __align__(16) char smem[17408];   // As 8K | Bs 8K ; Cs/Cs8 alias
  uchar* As = (uchar*)smem;
  uchar* Bs = (uchar*)(smem + 8192);
  bf16 (*Cs)[136] = (bf16 (*)[136])smem;
  uchar (*Cs8)[144] = (uchar (*)[144])smem;
  int chunk = gridDim.x >> 3;
  int bi = (blockIdx.x & 7) * chunk + (blockIdx.x >> 3);   // XCD-contiguous
  int m0 = (bi / nTiles) * 128, n0 = (bi % nTiles) * 128;
  int tid = threadIdx.x;
  int wave = tid >> 6, lane = tid & 63;
  int wm = (wave >> 1) * 64, wn = (wave & 1) * 64;
  int r = lane & 15, qd = lane >> 4;

  const uchar* ag[2]; const uchar* bg[2]; uchar* la[2]; uchar* lb[2];
  #pragma unroll
  for (int j = 0; j < 2; j++){
    int c = tid + j * 256;
    int row = c >> 2, pp = c & 3;
    int lco = pp ^ ((row >> 1) & 3);        // key = (row>>1)&3  [R11 fix]
    ag[j] = A  + (size_t)(m0 + row) * lda + lco * 16;
    bg[j] = Bt + (size_t)(n0 + row) * ldb + lco * 16;
    la[j] = As + (size_t)c * 16;
    lb[j] = Bs + (size_t)c * 16;
  }

  f32x4 acc[4][4];
  #pragma unroll
  for (int mt = 0; mt < 4; mt++)
    #pragma unroll
    for (int nt = 0; nt < 4; nt++) acc[mt][nt] = (f32x4){0.f, 0.f, 0.f, 0.f};

  for (int k0 = 0; k0 < K; k0 += 64){
    #pragma unroll
    for (int j = 0; j < 2; j++){ gl_lds16(ag[j], la[j]); gl_lds16(bg[j], lb[j]); }
    #pragma unroll
    for (int j = 0; j < 2; j++){ ag[j] += 64; bg[j] += 64; }
    __syncthreads();
    #pragma unroll
    for (int ph = 0; ph < 2; ph++){
      int l16 = ph * 2 + (qd >> 1);
      int woff = (qd & 1) * 8;
      i64 af[4], bfr[4];
      #pragma unroll
      for (int t = 0; t < 4; t++){
        int rowA = wm + t * 16 + r;
        int rowB = wn + t * 16 + r;
        int swA = ((l16 ^ ((rowA >> 1) & 3)) * 16) + woff;
        int swB = ((l16 ^ ((rowB >> 1) & 3)) * 16) + woff;
        af[t]  = *(const i64*)(As + rowA * 64 + swA);
        bfr[t] = *(const i64*)(Bs + rowB * 64 + swB);
      }
      #pragma unroll
      for (int mt = 0; mt < 4; mt++)
        #pragma unroll
        for (int nt = 0; nt < 4; nt++)
          acc[mt][nt] = __builtin_amdgcn_mfma_f32_16x16x32_fp8_fp8(af[mt], bfr[nt], acc[mt][nt], 0, 0, 0);
    }
    __syncthreads();
  }

  #pragma unroll
  for (int half = 0; half < 2; half++){
    if ((wave >> 1) == half){
      #pragma unroll
      for (int mt = 0; mt < 4; mt++)
        #pragma unroll
        for (int nt = 0; nt < 4; nt++)
          #pragma unroll
          for (int i = 0; i < 4; i++){
            int lm = mt * 16 + qd * 4 + i;
            int ln = wn + nt * 16 + r;
            float v = acc[mt][nt][i] + bias[n0 + ln];
            if (MODE == 2){
              Cs8[lm][ln] = f2f8(fmaxf(v, 0.0f));
            } else {
              Cs[lm][ln] = __float2bfloat16(v);
            }
          }
    }
    __syncthreads();
    int mbase = m0 + half * 64;
    if (MODE == 2){
      int lr = tid >> 2, seg = tid & 3;
      uchar* op = out8 + (size_t)(mbase + lr) * N + n0 + seg * 32;
      #pragma unroll
      for (int j = 0; j < 2; j++)
        *(uint4*)(op + j * 16) = *(uint4*)(&Cs8[lr][seg * 32 + j * 16]);
    } else {
      int lr = tid >> 2, seg = tid & 3;
      bf16* op = xres + (size_t)(mbase + lr) * 256 + n0 + seg * 32;
      #pragma unroll
      for (int j = 0; j < 4; j++){
        uint4 cv = *(uint4*)(&Cs[lr][seg * 32 + j * 8]);
        uint4 xv = *(uint4*)(op + j * 8);
        bf16* ca = (bf16*)&cv; bf16* xa = (bf16*)&xv;
        bf16 o8[8];
        #pragma unroll
        for (int t = 0; t < 8; t++)
          o8[t] = __float2bfloat16(__bfloat162float(ca[t]) + __bfloat162float(xa[t]));
        *(uint4*)(op + j * 8) = *(uint4*)o8;
      }
    }
    __syncthreads();
  }
}

// attn4: one block per (b_local,h), 512 thr / 8 waves, 3 q-tiles/wave,
// single-pass softmax (scores O(1); pad queries s=0 -> uniform). K LDS-resident.
__global__ __launch_bounds__(512) void attn4(
    const bf16* __restrict__ q, const bf16* __restrict__ kk, const bf16* __restrict__ vt,
    const int* __restrict__ src, bf16* __restrict__ ctx)
{
  __shared__ bf16 Ks[360][72];
  __shared__ bf16 Pb[8][16][48];
  int bh = blockIdx.x;
  int b = bh >> 2, h = bh & 3;
  int wave = threadIdx.x >> 6, lane = threadIdx.x & 63;
  int r = lane & 15, qd = lane >> 4;
  const bf16* qb = q  + (size_t)bh * 360 * 64;
  const bf16* kb = kk + (size_t)bh * 360 * 64;
  const bf16* vb = vt + (size_t)bh * 64 * 360;
  const int* srow = src + b * 360;

  for (int c = threadIdx.x; c < 2880; c += 512){
    int row = c >> 3, g = c & 7;
    *(uint4*)(&Ks[row][g * 8]) = *(const uint4*)(kb + row * 64 + g * 8);
  }
  __syncthreads();

  frag8 qa0[3], qa1[3];
  bool qp[3];
  float lsum[3];
  f32x4 accO[3][4];
  #pragma unroll
  for (int tl = 0; tl < 3; tl++){
    int qt = wave * 3 + tl;
    int qg = qt * 16 + r;
    int qrow = qg > 359 ? 359 : qg;
    qa0[tl] = *(const frag8*)(qb + qrow * 64 + qd * 8);
    qa1[tl] = *(const frag8*)(qb + qrow * 64 + 32 + qd * 8);
    qp[tl] = (qg < 360) && (srow[qg] == 799);
    lsum[tl] = 0.f;
    #pragma unroll
    for (int dt = 0; dt < 4; dt++) accO[tl][dt] = (f32x4){0.f, 0.f, 0.f, 0.f};
  }

  for (int kc = 0; kc < 12; kc++){
    int krow0 = kc * 32 + r;      if (krow0 > 359) krow0 = 359;
    int krow1 = kc * 32 + 16 + r; if (krow1 > 359) krow1 = 359;
    frag8 kf00 = *(const frag8*)(&Ks[krow0][qd * 8]);
    frag8 kf01 = *(const frag8*)(&Ks[krow0][32 + qd * 8]);
    frag8 kf10 = *(const frag8*)(&Ks[krow1][qd * 8]);
    frag8 kf11 = *(const frag8*)(&Ks[krow1][32 + qd * 8]);
    frag8 vf[4];
    #pragma unroll
    for (int dt = 0; dt < 4; dt++)
      vf[dt] = *(const frag8*)(vb + (size_t)(dt * 16 + r) * 360 + kc * 32 + qd * 8);

    #pragma unroll
    for (int tl = 0; tl < 3; tl++){
      f32x4 z0 = {0.f, 0.f, 0.f, 0.f}, z1 = {0.f, 0.f, 0.f, 0.f};
      z0 = __builtin_amdgcn_mfma_f32_16x16x32_bf16(kf00, qa0[tl], z0, 0, 0, 0);
      z0 = __builtin_amdgcn_mfma_f32_16x16x32_bf16(kf01, qa1[tl], z0, 0, 0, 0);
      z1 = __builtin_amdgcn_mfma_f32_16x16x32_bf16(kf10, qa0[tl], z1, 0, 0, 0);
      z1 = __builtin_amdgcn_mfma_f32_16x16x32_bf16(kf11, qa1[tl], z1, 0, 0, 0);
      float p0[4], p1[4];
      #pragma unroll
      for (int i = 0; i < 4; i++){
        int key0 = kc * 32 + qd * 4 + i;
        int key1 = key0 + 16;
        float s0 = z0[i] * 0.125f, s1 = z1[i] * 0.125f;
        if (qp[tl]){ s0 = 0.0f; s1 = 0.0f; }
        p0[i] = (key0 < 360) ? __expf(s0) : 0.0f;
        p1[i] = (key1 < 360) ? __expf(s1) : 0.0f;
        lsum[tl] += p0[i] + p1[i];
      }
      *(uint2*)(&Pb[wave][r][qd * 4])      = make_uint2(pack2(p0[0], p0[1]), pack2(p0[2], p0[3]));
      *(uint2*)(&Pb[wave][r][16 + qd * 4]) = make_uint2(pack2(p1[0], p1[1]), pack2(p1[2], p1[3]));
      asm volatile("s_waitcnt lgkmcnt(0)" ::: "memory");
      frag8 pa = *(const frag8*)(&Pb[wave][r][qd * 8]);
      #pragma unroll
      for (int dt = 0; dt < 4; dt++)
        accO[tl][dt] = __builtin_amdgcn_mfma_f32_16x16x32_bf16(pa, vf[dt], accO[tl][dt], 0, 0, 0);
      asm volatile("s_waitcnt lgkmcnt(0)" ::: "memory");
    }
  }

  #pragma unroll
  for (int tl = 0; tl < 3; tl++){
    int qt = wave * 3 + tl;
    float ls = lsum[tl];
    ls += __shfl_xor(ls, 16, 64);
    ls += __shfl_xor(ls, 32, 64);
    float invl = 1.0f / ls;
    #pragma unroll
    for (int i = 0; i < 4; i++){
      float inv_i = __shfl(invl, qd * 4 + i, 64);
      int qglob = qt * 16 + qd * 4 + i;
      if (qglob < 360){
        #pragma unroll
        for (int dt = 0; dt < 4; dt++)
          ctx[((size_t)(b * 360 + qglob)) * 256 + h * 64 + dt * 16 + r] =
              __float2bfloat16(accO[tl][dt][i] * inv_i);
      }
    }
  }
}

// head: one block per batch (grid 256, 4 waves). x rows 0..191 staged in LDS,
// wl register-resident per lane, waves sweep pairs p = wave, wave+4, ...
__global__ __launch_bounds__(256) void head_k(
    const bf16* __restrict__ x, const int* __restrict__ src,
    const float* __restrict__ wl, const float* __restrict__ bl,
    float* __restrict__ out)
{
  __shared__ bf16 Xs[192][264];
  int b = blockIdx.x;
  int tid = threadIdx.x;
  int wave = tid >> 6, lane = tid & 63;
  int g = lane >> 3, sub = lane & 7;

  const bf16* xb = x + (size_t)b * 360 * 256;
  for (int it = 0; it < 24; it++){
    int idx = tid + it * 256;
    int row = idx >> 5, col = idx & 31;
    *(uint4*)(&Xs[row][col * 8]) = *(const uint4*)(xb + row * 256 + col * 8);
  }

  float wv[96];
  {
    const float4* wr4 = (const float4*)(wl + (size_t)(g * 256 + sub * 32) * 3);
    #pragma unroll
    for (int c = 0; c < 24; c++) *(float4*)(&wv[c * 4]) = wr4[c];
  }
  float bl0 = bl[0], bl1 = bl[1], bl2 = bl[2];
  const int* sr = src + b * 360;
  __syncthreads();

  for (int p = wave; p < 91; p += 4){
    int i = 0, rem = p;
    while (rem >= 13 - i){ rem -= 13 - i; i++; }
    int j = i + 1 + rem;
    int base = 12 * i - (i * (i - 1)) / 2;
    int pe = base + (j - i) - 1;
    int eb = 28 + 2 * pe;

    int idxg;
    if (g == 0) idxg = 2 * i;
    else if (g == 1) idxg = 2 * i + 1;
    else if (g == 2) idxg = 2 * j;
    else if (g == 3) idxg = 2 * j + 1;
    else idxg = eb + (g - 4);
    bool zm = !(g >= 4 && j == 13);

    uint4 xv[4];
    #pragma unroll
    for (int c = 0; c < 4; c++) xv[c] = *(uint4*)(&Xs[idxg][sub * 32 + c * 8]);
    const bf16* xa = (const bf16*)xv;
    float a0 = 0.f, a1 = 0.f, a2 = 0.f;
    #pragma unroll
    for (int t = 0; t < 32; t++){
      float f = zm ? __bfloat162float(xa[t]) : 0.0f;
      a0 += f * wv[t * 3 + 0];
      a1 += f * wv[t * 3 + 1];
      a2 += f * wv[t * 3 + 2];
    }
    #pragma unroll
    for (int o = 1; o < 64; o <<= 1){
      a0 += __shfl_xor(a0, o, 64);
      a1 += __shfl_xor(a1, o, 64);
      a2 += __shfl_xor(a2, o, 64);
    }
    if (lane == 0){
      int ti = sr[2 * i], ai = sr[2 * i + 1], tj = sr[2 * j], aj = sr[2 * j + 1];
      bool c1 = (ai == 2) || (aj == 2);
      bool c2 = (tj == 1) || (ai == 1) || (aj == 1);
      bool c3 = (ti == 799) || (tj == 799) || (ai == 0) || (aj == 0);
      bool c4 = false;
      if (j < 13){
        int es = 28 + 4 * pe;
        c4 = (sr[es] == 1) || (sr[es + 1] == 1) || (sr[es + 2] == 1) || (sr[es + 3] == 1);
      }
      bool m1 = c3 || c4, m2 = m1 || c2, m3 = m2 || c1;
      float* op = out + ((size_t)b * 91 + p) * 3;
      op[0] = m1 ? -1.0e9f : (a0 + bl0);
      op[1] = m2 ? -1.0e9f : (a1 + bl1);
      op[2] = m3 ? -1.0e9f : (a2 + bl2);
    }
  }
}

extern "C" void kernel_launch(void* const* d_in, const int* in_sizes, int n_in,
                              void* d_out, int out_size, void* d_ws, size_t ws_size,
                              hipStream_t stream)
{
  const int*   src = (const int*)  d_in[0];
  const float* emb = (const float*)d_in[1];
  const float* wq  = (const float*)d_in[2];  const float* bq = (const float*)d_in[3];
  const float* wk  = (const float*)d_in[4];  const float* bk = (const float*)d_in[5];
  const float* wv  = (const float*)d_in[6];  const float* bv = (const float*)d_in[7];
  const float* wo  = (const float*)d_in[8];  const float* bo = (const float*)d_in[9];
  const float* n1a = (const float*)d_in[10]; const float* n1b = (const float*)d_in[11];
  const float* n2a = (const float*)d_in[12]; const float* n2b = (const float*)d_in[13];
  const float* w1  = (const float*)d_in[14]; const float* b1 = (const float*)d_in[15];
  const float* w2  = (const float*)d_in[16]; const float* b2 = (const float*)d_in[17];
  const float* wl  = (const float*)d_in[18]; const float* bl = (const float*)d_in[19];
  float* out = (float*)d_out;

  if (ws_size < 191365120ull) return;

  char* ws = (char*)d_ws;
  bf16* x   = (bf16*)(ws);                    // [92160][256] bf16
  bf16* xn  = (bf16*)(ws + 47185920ull);      // [92160][256] bf16 (LN1)
  char* R   = ws + 94371840ull;
  bf16* qh   = (bf16*)(R);                    // attn phase
  bf16* kh   = (bf16*)(R + 23592960ull);
  bf16* vth  = (bf16*)(R + 47185920ull);
  bf16* ctxh = (bf16*)(R + 70778880ull);
  uchar* h8  = (uchar*)(R);                   // ffn: [23040][2048] fp8
  uchar* xn8 = (uchar*)(R + 47185920ull);     // ffn: [92160][256] fp8 (LN2)
  char* wC   = ws + 188743680ull;
  bf16* wqT = (bf16*)(wC);
  bf16* wkT = (bf16*)(wC + 131072);
  bf16* wvT = (bf16*)(wC + 262144);
  bf16* woT = (bf16*)(wC + 393216);
  uchar* w1f8T = (uchar*)(wC + 524288);       // [2048][256] fp8
  uchar* w2f8T = (uchar*)(wC + 1048576);      // [256][2048] fp8

  cvt_all<<<1280, 256, 0, stream>>>(wq, wk, wv, wo, w1, w2,
                                    wqT, wkT, wvT, woT, w1f8T, w2f8T);

  embed_ln1<<<23040, 256, 0, stream>>>(src, emb, n1a, n1b, x, xn);

  for (int half = 0; half < 2; half++){
    size_t ro = (size_t)half * 46080;
    const bf16* xnh = xn + ro * 256;
    gemm_bt<4><<<2160, 256, 0, stream>>>(xnh, 256, wqT, 256, nullptr, qh, nullptr,
                                         768, 256, 6, bq, bk, bv);
    attn4<<<512, 512, 0, stream>>>(qh, kh, vth, src + ro, ctxh);
    gemm_bt<3><<<720, 256, 0, stream>>>(ctxh, 256, woT, 256, bo, nullptr, x + ro * 256,
                                        256, 256, 2, nullptr, nullptr, nullptr);
  }

  ln_k8<<<23040, 256, 0, stream>>>(x, n2a, n2b, xn8);

  for (int mc = 0; mc < 4; mc++){
    const uchar* xnc = xn8 + (size_t)mc * 23040 * 256;
    bf16* xc = x + (size_t)mc * 23040 * 256;
    gemm_f8<2><<<2880, 256, 0, stream>>>(xnc, 256, w1f8T, 256, b1, h8, nullptr,
                                         2048, 256, 16);
    gemm_f8<3><<<360, 256, 0, stream>>>(h8, 2048, w2f8T, 2048, b2, nullptr, xc,
                                        256, 2048, 2);
  }

  head_k<<<256, 256, 0, stream>>>(x, src, wl, bl, out);
}

// Round 13
// 745.490 us; speedup vs baseline: 1.2963x; 1.0552x over previous
//
#include <hip/hip_runtime.h>
#include <hip/hip_bf16.h>
#include <math.h>

// ---------------------------------------------------------------------------
// Round 12: full fp8 attention phase (slack: absmax 0.25 vs thr 2e7).
// - LN1 -> fp8 xn8; QKV = one full-M fp8 GEMM (grid 4320, MODE4 epilogue
//   -> q8/k8/vt8, 70.8MB fits R: no more half-passes).
// - attn5 = attn4 in fp8: K LDS stride 80 (16B-aligned, 2-way banks), fp8 P,
//   fp8 V frags, ctx8 staged through LDS -> coalesced 16B stores into the
//   dead xn8 buffer. WO = gemm_f8<3> full-M. gemm_bt deleted.
// ws: x 47.2M | xn8 23.6M @47185920 | R @70778880 (q8,k8,vt8 = 70.8M; ffn h8
// aliases R+0) | weights fp8 @141557760 (~1.3M). guard unchanged.
// ---------------------------------------------------------------------------

using bf16 = __hip_bfloat16;
typedef __attribute__((ext_vector_type(4))) float f32x4;
typedef long long i64;
typedef unsigned char uchar;

static __device__ __forceinline__ float wave_sum64(float v){
  #pragma unroll
  for (int o = 32; o >= 1; o >>= 1) v += __shfl_xor(v, o, 64);
  return v;
}

static __device__ __forceinline__ void gl_lds16(const void* g, void* l){
  __builtin_amdgcn_global_load_lds((const __attribute__((address_space(1))) void*)g,
                                   (__attribute__((address_space(3))) void*)l, 16, 0, 0);
}

static __device__ __forceinline__ uchar f2f8(float v){
  return (uchar)(__builtin_amdgcn_cvt_pk_fp8_f32(v, 0.f, 0, false) & 0xff);
}
static __device__ __forceinline__ unsigned pack4_fp8(float a, float b, float c, float d){
  int v = __builtin_amdgcn_cvt_pk_fp8_f32(a, b, 0, false);
  v = __builtin_amdgcn_cvt_pk_fp8_f32(c, d, v, true);
  return (unsigned)v;
}

// merged weight prep: all 6 jobs fp8 transposed. d0..d2 = wqkv8 row blocks.
__global__ __launch_bounds__(256) void cvt_all(
    const float* s0, const float* s1, const float* s2, const float* s3,
    const float* s4, const float* s5,
    uchar* d0, uchar* d1, uchar* d2, uchar* d3, uchar* d4, uchar* d5)
{
  __shared__ float t[32][33];
  const float* srcs[6] = {s0, s1, s2, s3, s4, s5};
  uchar* dsts[6] = {d0, d1, d2, d3, d4, d5};
  const int Ks[6] = {256, 256, 256, 256, 256, 2048};
  const int Ns[6] = {256, 256, 256, 256, 2048, 256};
  const int offs[7] = {0, 64, 128, 192, 256, 768, 1280};
  int bid = blockIdx.x, j = 5;
  #pragma unroll
  for (int q = 4; q >= 0; q--) if (bid < offs[q + 1]) j = q;
  int local = bid - offs[j];
  int K = Ks[j], N = Ns[j];
  const float* src = srcs[j];
  uchar* dst = dsts[j];
  int kt = K >> 5;
  int kb = (local % kt) * 32, nb = (local / kt) * 32;
  int tx = threadIdx.x & 31, ty = threadIdx.x >> 5;
  #pragma unroll
  for (int dy = 0; dy < 32; dy += 8)
    t[ty + dy][tx] = src[(size_t)(kb + ty + dy) * N + nb + tx];
  __syncthreads();
  #pragma unroll
  for (int dy = 0; dy < 32; dy += 8)
    dst[(size_t)(nb + ty + dy) * K + kb + tx] = f2f8(t[tx][ty + dy]);
}

// embed + PE + scale -> x (bf16), LN1 -> fp8 xn8. one wave/row, grid 23040.
__global__ __launch_bounds__(256) void embed_ln1(
    const int* __restrict__ src, const float* __restrict__ emb,
    const float* __restrict__ na, const float* __restrict__ nb,
    bf16* __restrict__ x, uchar* __restrict__ xn8)
{
  int row  = blockIdx.x * 4 + (threadIdx.x >> 6);
  int lane = threadIdx.x & 63;
  int s = row % 360;
  int tok = src[row];
  float4 v = *(const float4*)(emb + (size_t)tok * 256 + lane * 4);
  float vv[4] = {v.x, v.y, v.z, v.w};
  if (s < 340){
    const float C = (-2.0f / 256.0f) * 13.287712379549449f;
    #pragma unroll
    for (int t = 0; t < 4; t++){
      int c = lane * 4 + t;
      float ang = (float)s * exp2f(C * (float)c);
      float pe = (c & 1) ? cosf(ang) : sinf(ang);
      vv[t] = 16.0f * vv[t] + pe;
    }
  }
  float sum = wave_sum64(vv[0] + vv[1] + vv[2] + vv[3]);
  float mu = sum * (1.0f / 256.0f);
  float d0 = vv[0]-mu, d1 = vv[1]-mu, d2 = vv[2]-mu, d3 = vv[3]-mu;
  float sq = wave_sum64(d0*d0 + d1*d1 + d2*d2 + d3*d3);
  float inv = 1.0f / (sqrtf(sq * (1.0f / 255.0f)) + 1e-6f);
  bf16 xo[4] = { __float2bfloat16(vv[0]), __float2bfloat16(vv[1]),
                 __float2bfloat16(vv[2]), __float2bfloat16(vv[3]) };
  *(uint2*)(x + (size_t)row * 256 + lane * 4) = *(uint2*)xo;
  float4 a4 = *(const float4*)(na + lane * 4);
  float4 b4 = *(const float4*)(nb + lane * 4);
  unsigned u = pack4_fp8(a4.x * d0 * inv + b4.x, a4.y * d1 * inv + b4.y,
                         a4.z * d2 * inv + b4.z, a4.w * d3 * inv + b4.w);
  *(unsigned*)(xn8 + (size_t)row * 256 + lane * 4) = u;
}

// LN2 over bf16 x -> fp8 xn8. one wave per row. grid 23040.
__global__ __launch_bounds__(256) void ln_k8(
    const bf16* __restrict__ x, const float* __restrict__ na,
    const float* __restrict__ nb, uchar* __restrict__ xn8)
{
  int row  = blockIdx.x * 4 + (threadIdx.x >> 6);
  int lane = threadIdx.x & 63;
  uint2 raw = *(const uint2*)(x + (size_t)row * 256 + lane * 4);
  bf16* xr = (bf16*)&raw;
  float v0 = __bfloat162float(xr[0]), v1 = __bfloat162float(xr[1]);
  float v2 = __bfloat162float(xr[2]), v3 = __bfloat162float(xr[3]);
  float sum = wave_sum64(v0 + v1 + v2 + v3);
  float mu = sum * (1.0f / 256.0f);
  float d0 = v0-mu, d1 = v1-mu, d2 = v2-mu, d3 = v3-mu;
  float sq = wave_sum64(d0*d0 + d1*d1 + d2*d2 + d3*d3);
  float inv = 1.0f / (sqrtf(sq * (1.0f / 255.0f)) + 1e-6f);
  float4 a4 = *(const float4*)(na + lane * 4);
  float4 b4 = *(const float4*)(nb + lane * 4);
  unsigned u = pack4_fp8(a4.x * d0 * inv + b4.x, a4.y * d1 * inv + b4.y,
                         a4.z * d2 * inv + b4.z, a4.w * d3 * inv + b4.w);
  *(unsigned*)(xn8 + (size_t)row * 256 + lane * 4) = u;
}

// fp8 GEMM: C = A[M][K](e4m3) @ Bt[N][K]^T(e4m3). 128x128 tile, BK=64,
// 16B-granule XOR swizzle key (row>>1)&3, XCD-aware block remap.
// MODE 2: relu -> fp8 row-major [M][N]
// MODE 3: bf16 residual in-place += acc (+bias)
// MODE 4: merged QKV (N=768): region n0>>8: 0 q8-layout, 1 k8-layout, 2 v^T8
template<int MODE>
__global__ __launch_bounds__(256) void gemm_f8(
    const uchar* __restrict__ A, int lda,
    const uchar* __restrict__ Bt, int ldb,
    const float* __restrict__ bias,
    uchar* __restrict__ out8, bf16* __restrict__ xres,
    int N, int K, int nTiles,
    const float* __restrict__ bq, const float* __restrict__ bk,
    const float* __restrict__ bv)
{
  __shared__ __align__(16) char smem[17408];   // As 8K | Bs 8K ; Cs/Cs8 alias
  uchar* As = (uchar*)smem;
  uchar* Bs = (uchar*)(smem + 8192);
  bf16 (*Cs)[136] = (bf16 (*)[136])smem;
  uchar (*Cs8)[144] = (uchar (*)[144])smem;
  int chunk = gridDim.x >> 3;
  int bi = (blockIdx.x & 7) * chunk + (blockIdx.x >> 3);   // XCD-contiguous
  int m0 = (bi / nTiles) * 128, n0 = (bi % nTiles) * 128;
  int tid = threadIdx.x;
  int wave = tid >> 6, lane = tid & 63;
  int wm = (wave >> 1) * 64, wn = (wave & 1) * 64;
  int r = lane & 15, qd = lane >> 4;

  const uchar* ag[2]; const uchar* bg[2]; uchar* la[2]; uchar* lb[2];
  #pragma unroll
  for (int j = 0; j < 2; j++){
    int c = tid + j * 256;
    int row = c >> 2, pp = c & 3;
    int lco = pp ^ ((row >> 1) & 3);
    ag[j] = A  + (size_t)(m0 + row) * lda + lco * 16;
    bg[j] = Bt + (size_t)(n0 + row) * ldb + lco * 16;
    la[j] = As + (size_t)c * 16;
    lb[j] = Bs + (size_t)c * 16;
  }

  f32x4 acc[4][4];
  #pragma unroll
  for (int mt = 0; mt < 4; mt++)
    #pragma unroll
    for (int nt = 0; nt < 4; nt++) acc[mt][nt] = (f32x4){0.f, 0.f, 0.f, 0.f};

  for (int k0 = 0; k0 < K; k0 += 64){
    #pragma unroll
    for (int j = 0; j < 2; j++){ gl_lds16(ag[j], la[j]); gl_lds16(bg[j], lb[j]); }
    #pragma unroll
    for (int j = 0; j < 2; j++){ ag[j] += 64; bg[j] += 64; }
    __syncthreads();
    #pragma unroll
    for (int ph = 0; ph < 2; ph++){
      int l16 = ph * 2 + (qd >> 1);
      int woff = (qd & 1) * 8;
      i64 af[4], bfr[4];
      #pragma unroll
      for (int t = 0; t < 4; t++){
        int rowA = wm + t * 16 + r;
        int rowB = wn + t * 16 + r;
        int swA = ((l16 ^ ((rowA >> 1) & 3)) * 16) + woff;
        int swB = ((l16 ^ ((rowB >> 1) & 3)) * 16) + woff;
        af[t]  = *(const i64*)(As + rowA * 64 + swA);
        bfr[t] = *(const i64*)(Bs + rowB * 64 + swB);
      }
      #pragma unroll
      for (int mt = 0; mt < 4; mt++)
        #pragma unroll
        for (int nt = 0; nt < 4; nt++)
          acc[mt][nt] = __builtin_amdgcn_mfma_f32_16x16x32_fp8_fp8(af[mt], bfr[nt], acc[mt][nt], 0, 0, 0);
    }
    __syncthreads();
  }

  const int region = (MODE == 4) ? (n0 >> 8) : 0;
  const float* bb = (MODE == 4) ? (region == 0 ? bq : region == 1 ? bk : bv) : bias;

  #pragma unroll
  for (int half = 0; half < 2; half++){
    if ((wave >> 1) == half){
      #pragma unroll
      for (int mt = 0; mt < 4; mt++)
        #pragma unroll
        for (int nt = 0; nt < 4; nt++)
          #pragma unroll
          for (int i = 0; i < 4; i++){
            int lm = mt * 16 + qd * 4 + i;
            int ln = wn + nt * 16 + r;
            float v = acc[mt][nt][i];
            if (MODE == 2){ v += bb[n0 + ln]; Cs8[lm][ln] = f2f8(fmaxf(v, 0.0f)); }
            else if (MODE == 3){ if (bb) v += bb[n0 + ln]; Cs[lm][ln] = __float2bfloat16(v); }
            else { v += bb[(n0 & 255) + ln]; Cs8[lm][ln] = f2f8(v); }
          }
    }
    __syncthreads();
    int mbase = m0 + half * 64;
    if (MODE == 2){
      int lr = tid >> 2, seg = tid & 3;
      uchar* op = out8 + (size_t)(mbase + lr) * N + n0 + seg * 32;
      #pragma unroll
      for (int j = 0; j < 2; j++)
        *(uint4*)(op + j * 16) = *(uint4*)(&Cs8[lr][seg * 32 + j * 16]);
    } else if (MODE == 3){
      int lr = tid >> 2, seg = tid & 3;
      bf16* op = xres + (size_t)(mbase + lr) * 256 + n0 + seg * 32;
      #pragma unroll
      for (int j = 0; j < 4; j++){
        uint4 cv = *(uint4*)(&Cs[lr][seg * 32 + j * 8]);
        uint4 xv = *(uint4*)(op + j * 8);
        bf16* ca = (bf16*)&cv; bf16* xa = (bf16*)&xv;
        bf16 o8[8];
        #pragma unroll
        for (int t = 0; t < 8; t++)
          o8[t] = __float2bfloat16(__bfloat162float(ca[t]) + __bfloat162float(xa[t]));
        *(uint4*)(op + j * 8) = *(uint4*)o8;
      }
    } else {  // MODE 4
      if (region < 2){
        // q8/k8 [bh][360][64] fp8: 64 rows x 128B = 256 thr x 32B
        int lr = tid >> 2, seg = tid & 3;
        int m = mbase + lr;
        int b_ = m / 360, s = m - b_ * 360;
        int nnl = (n0 & 255) + seg * 32;
        int h = nnl >> 6, dk = nnl & 63;
        size_t roff = (region == 1) ? 23592960ull : 0ull;
        uchar* op = out8 + roff + ((size_t)(b_ * 4 + h) * 360 + s) * 64 + dk;
        #pragma unroll
        for (int j = 0; j < 2; j++)
          *(uint4*)(op + j * 16) = *(uint4*)(&Cs8[lr][seg * 32 + j * 16]);
      } else {
        // v^T8 [bh][64][360] fp8: in-LDS gather, 8B stores (s is 8-aligned)
        int nn = tid >> 1;
        int nnl = (n0 & 255) + nn;
        int h = nnl >> 6, dk = nnl & 63;
        int msub = (tid & 1) * 32;
        #pragma unroll
        for (int j0 = 0; j0 < 32; j0 += 8){
          int m = mbase + msub + j0;
          int b_ = m / 360, s = m - b_ * 360;
          uchar tmp[8];
          #pragma unroll
          for (int t = 0; t < 8; t++) tmp[t] = Cs8[msub + j0 + t][nn];
          *(uint2*)(out8 + 47185920ull + ((size_t)((b_ * 4 + h) * 64 + dk)) * 360 + s) =
              *(uint2*)tmp;
        }
      }
    }
    __syncthreads();
  }
}

// attn5: fp8 flash attention. one block per (b,h) [1024], 512 thr / 8 waves,
// 3 q-tiles/wave, single-pass softmax (pad queries s=0 -> uniform).
// K LDS-resident (stride 80B: 16B-aligned, 2-way banks). ctx8 staged via LDS.
__global__ __launch_bounds__(512) void attn5(
    const uchar* __restrict__ q, const uchar* __restrict__ kk, const uchar* __restrict__ vt,
    const int* __restrict__ src, uchar* __restrict__ ctx8)
{
  __shared__ uchar Ks[360][80];
  __shared__ uchar Pb[8][16][48];
  __shared__ uchar Cb[8][16][80];
  int bh = blockIdx.x;
  int b = bh >> 2, h = bh & 3;
  int wave = threadIdx.x >> 6, lane = threadIdx.x & 63;
  int r = lane & 15, qd = lane >> 4;
  const uchar* qb = q  + (size_t)bh * 360 * 64;
  const uchar* kb = kk + (size_t)bh * 360 * 64;
  const uchar* vb = vt + (size_t)bh * 64 * 360;
  const int* srow = src + b * 360;

  for (int c = threadIdx.x; c < 1440; c += 512){     // 360 rows x 4 x 16B
    int row = c >> 2, g = c & 3;
    *(uint4*)(&Ks[row][g * 16]) = *(const uint4*)(kb + row * 64 + g * 16);
  }
  __syncthreads();

  i64 qa0[3], qa1[3];
  bool qp[3];
  float lsum[3];
  f32x4 accO[3][4];
  #pragma unroll
  for (int tl = 0; tl < 3; tl++){
    int qt = wave * 3 + tl;
    int qg = qt * 16 + r;
    int qrow = qg > 359 ? 359 : qg;
    qa0[tl] = *(const i64*)(qb + qrow * 64 + qd * 8);
    qa1[tl] = *(const i64*)(qb + qrow * 64 + 32 + qd * 8);
    qp[tl] = (qg < 360) && (srow[qg] == 799);
    lsum[tl] = 0.f;
    #pragma unroll
    for (int dt = 0; dt < 4; dt++) accO[tl][dt] = (f32x4){0.f, 0.f, 0.f, 0.f};
  }

  for (int kc = 0; kc < 12; kc++){
    int krow0 = kc * 32 + r;      if (krow0 > 359) krow0 = 359;
    int krow1 = kc * 32 + 16 + r; if (krow1 > 359) krow1 = 359;
    i64 kf00 = *(const i64*)(&Ks[krow0][qd * 8]);
    i64 kf01 = *(const i64*)(&Ks[krow0][32 + qd * 8]);
    i64 kf10 = *(const i64*)(&Ks[krow1][qd * 8]);
    i64 kf11 = *(const i64*)(&Ks[krow1][32 + qd * 8]);
    i64 vf[4];
    #pragma unroll
    for (int dt = 0; dt < 4; dt++)
      vf[dt] = *(const i64*)(vb + (size_t)(dt * 16 + r) * 360 + kc * 32 + qd * 8);

    #pragma unroll
    for (int tl = 0; tl < 3; tl++){
      f32x4 z0 = {0.f, 0.f, 0.f, 0.f}, z1 = {0.f, 0.f, 0.f, 0.f};
      z0 = __builtin_amdgcn_mfma_f32_16x16x32_fp8_fp8(kf00, qa0[tl], z0, 0, 0, 0);
      z0 = __builtin_amdgcn_mfma_f32_16x16x32_fp8_fp8(kf01, qa1[tl], z0, 0, 0, 0);
      z1 = __builtin_amdgcn_mfma_f32_16x16x32_fp8_fp8(kf10, qa0[tl], z1, 0, 0, 0);
      z1 = __builtin_amdgcn_mfma_f32_16x16x32_fp8_fp8(kf11, qa1[tl], z1, 0, 0, 0);
      float p0[4], p1[4];
      #pragma unroll
      for (int i = 0; i < 4; i++){
        int key0 = kc * 32 + qd * 4 + i;
        int key1 = key0 + 16;
        float s0 = z0[i] * 0.125f, s1 = z1[i] * 0.125f;
        if (qp[tl]){ s0 = 0.0f; s1 = 0.0f; }
        p0[i] = (key0 < 360) ? __expf(s0) : 0.0f;
        p1[i] = (key1 < 360) ? __expf(s1) : 0.0f;
        lsum[tl] += p0[i] + p1[i];
      }
      *(unsigned*)(&Pb[wave][r][qd * 4])      = pack4_fp8(p0[0], p0[1], p0[2], p0[3]);
      *(unsigned*)(&Pb[wave][r][16 + qd * 4]) = pack4_fp8(p1[0], p1[1], p1[2], p1[3]);
      asm volatile("s_waitcnt lgkmcnt(0)" ::: "memory");
      i64 pa = *(const i64*)(&Pb[wave][r][qd * 8]);
      #pragma unroll
      for (int dt = 0; dt < 4; dt++)
        accO[tl][dt] = __builtin_amdgcn_mfma_f32_16x16x32_fp8_fp8(pa, vf[dt], accO[tl][dt], 0, 0, 0);
      asm volatile("s_waitcnt lgkmcnt(0)" ::: "memory");
    }
  }

  #pragma unroll
  for (int tl = 0; tl < 3; tl++){
    int qt = wave * 3 + tl;
    float ls = lsum[tl];
    ls += __shfl_xor(ls, 16, 64);
    ls += __shfl_xor(ls, 32, 64);
    float invl = 1.0f / ls;
    #pragma unroll
    for (int i = 0; i < 4; i++){
      float inv_i = __shfl(invl, qd * 4 + i, 64);
      #pragma unroll
      for (int dt = 0; dt < 4; dt++)
        Cb[wave][qd * 4 + i][dt * 16 + r] = f2f8(accO[tl][dt][i] * inv_i);
    }
    asm volatile("s_waitcnt lgkmcnt(0)" ::: "memory");
    int qglob = qt * 16 + r;
    if (qglob < 360)
      *(uint4*)(ctx8 + ((size_t)(b * 360 + qglob)) * 256 + h * 64 + qd * 16) =
          *(uint4*)(&Cb[wave][r][qd * 16]);
    asm volatile("s_waitcnt lgkmcnt(0)" ::: "memory");  // WAR before next tl
  }
}

// head: one block per batch (grid 256, 4 waves). x rows 0..191 staged in LDS,
// wl register-resident per lane, waves sweep pairs p = wave, wave+4, ...
__global__ __launch_bounds__(256) void head_k(
    const bf16* __restrict__ x, const int* __restrict__ src,
    const float* __restrict__ wl, const float* __restrict__ bl,
    float* __restrict__ out)
{
  __shared__ bf16 Xs[192][264];
  int b = blockIdx.x;
  int tid = threadIdx.x;
  int wave = tid >> 6, lane = tid & 63;
  int g = lane >> 3, sub = lane & 7;

  const bf16* xb = x + (size_t)b * 360 * 256;
  for (int it = 0; it < 24; it++){
    int idx = tid + it * 256;
    int row = idx >> 5, col = idx & 31;
    *(uint4*)(&Xs[row][col * 8]) = *(const uint4*)(xb + row * 256 + col * 8);
  }

  float wv[96];
  {
    const float4* wr4 = (const float4*)(wl + (size_t)(g * 256 + sub * 32) * 3);
    #pragma unroll
    for (int c = 0; c < 24; c++) *(float4*)(&wv[c * 4]) = wr4[c];
  }
  float bl0 = bl[0], bl1 = bl[1], bl2 = bl[2];
  const int* sr = src + b * 360;
  __syncthreads();

  for (int p = wave; p < 91; p += 4){
    int i = 0, rem = p;
    while (rem >= 13 - i){ rem -= 13 - i; i++; }
    int j = i + 1 + rem;
    int base = 12 * i - (i * (i - 1)) / 2;
    int pe = base + (j - i) - 1;
    int eb = 28 + 2 * pe;

    int idxg;
    if (g == 0) idxg = 2 * i;
    else if (g == 1) idxg = 2 * i + 1;
    else if (g == 2) idxg = 2 * j;
    else if (g == 3) idxg = 2 * j + 1;
    else idxg = eb + (g - 4);
    bool zm = !(g >= 4 && j == 13);

    uint4 xv[4];
    #pragma unroll
    for (int c = 0; c < 4; c++) xv[c] = *(uint4*)(&Xs[idxg][sub * 32 + c * 8]);
    const bf16* xa = (const bf16*)xv;
    float a0 = 0.f, a1 = 0.f, a2 = 0.f;
    #pragma unroll
    for (int t = 0; t < 32; t++){
      float f = zm ? __bfloat162float(xa[t]) : 0.0f;
      a0 += f * wv[t * 3 + 0];
      a1 += f * wv[t * 3 + 1];
      a2 += f * wv[t * 3 + 2];
    }
    #pragma unroll
    for (int o = 1; o < 64; o <<= 1){
      a0 += __shfl_xor(a0, o, 64);
      a1 += __shfl_xor(a1, o, 64);
      a2 += __shfl_xor(a2, o, 64);
    }
    if (lane == 0){
      int ti = sr[2 * i], ai = sr[2 * i + 1], tj = sr[2 * j], aj = sr[2 * j + 1];
      bool c1 = (ai == 2) || (aj == 2);
      bool c2 = (tj == 1) || (ai == 1) || (aj == 1);
      bool c3 = (ti == 799) || (tj == 799) || (ai == 0) || (aj == 0);
      bool c4 = false;
      if (j < 13){
        int es = 28 + 4 * pe;
        c4 = (sr[es] == 1) || (sr[es + 1] == 1) || (sr[es + 2] == 1) || (sr[es + 3] == 1);
      }
      bool m1 = c3 || c4, m2 = m1 || c2, m3 = m2 || c1;
      float* op = out + ((size_t)b * 91 + p) * 3;
      op[0] = m1 ? -1.0e9f : (a0 + bl0);
      op[1] = m2 ? -1.0e9f : (a1 + bl1);
      op[2] = m3 ? -1.0e9f : (a2 + bl2);
    }
  }
}

extern "C" void kernel_launch(void* const* d_in, const int* in_sizes, int n_in,
                              void* d_out, int out_size, void* d_ws, size_t ws_size,
                              hipStream_t stream)
{
  const int*   src = (const int*)  d_in[0];
  const float* emb = (const float*)d_in[1];
  const float* wq  = (const float*)d_in[2];  const float* bq = (const float*)d_in[3];
  const float* wk  = (const float*)d_in[4];  const float* bk = (const float*)d_in[5];
  const float* wv  = (const float*)d_in[6];  const float* bv = (const float*)d_in[7];
  const float* wo  = (const float*)d_in[8];  const float* bo = (const float*)d_in[9];
  const float* n1a = (const float*)d_in[10]; const float* n1b = (const float*)d_in[11];
  const float* n2a = (const float*)d_in[12]; const float* n2b = (const float*)d_in[13];
  const float* w1  = (const float*)d_in[14]; const float* b1 = (const float*)d_in[15];
  const float* w2  = (const float*)d_in[16]; const float* b2 = (const float*)d_in[17];
  const float* wl  = (const float*)d_in[18]; const float* bl = (const float*)d_in[19];
  float* out = (float*)d_out;

  if (ws_size < 191365120ull) return;

  char* ws = (char*)d_ws;
  bf16*  x    = (bf16*)(ws);                   // [92160][256] bf16
  uchar* xn8  = (uchar*)(ws + 47185920ull);    // [92160][256] fp8: LN1 / ctx8 / LN2
  char*  R    = ws + 70778880ull;
  uchar* q8   = (uchar*)(R);                   // [1024][360][64]; k8 +23592960; vt8 +47185920
  uchar* k8   = (uchar*)(R + 23592960ull);
  uchar* vt8  = (uchar*)(R + 47185920ull);     // [1024][64][360]
  uchar* h8   = (uchar*)(R);                   // ffn: [23040][2048] fp8 (aliases q8/k8)
  char*  wC   = ws + 141557760ull;
  uchar* wqkv8 = (uchar*)(wC);                 // [768][256] fp8
  uchar* wo8   = (uchar*)(wC + 196608);        // [256][256] fp8
  uchar* w1f8T = (uchar*)(wC + 262144);        // [2048][256] fp8
  uchar* w2f8T = (uchar*)(wC + 786432);        // [256][2048] fp8

  cvt_all<<<1280, 256, 0, stream>>>(wq, wk, wv, wo, w1, w2,
                                    wqkv8, wqkv8 + 65536, wqkv8 + 131072,
                                    wo8, w1f8T, w2f8T);

  embed_ln1<<<23040, 256, 0, stream>>>(src, emb, n1a, n1b, x, xn8);

  // QKV: full M in one dispatch. 720 m-tiles x 6 n-tiles = 4320 blocks.
  gemm_f8<4><<<4320, 256, 0, stream>>>(xn8, 256, wqkv8, 256, nullptr, q8, nullptr,
                                       768, 256, 6, bq, bk, bv);

  attn5<<<1024, 512, 0, stream>>>(q8, k8, vt8, src, xn8 /* ctx8 */);

  // WO: full M, residual into x. 720 x 2 = 1440 blocks.
  gemm_f8<3><<<1440, 256, 0, stream>>>(xn8, 256, wo8, 256, bo, nullptr, x,
                                       256, 256, 2, nullptr, nullptr, nullptr);

  ln_k8<<<23040, 256, 0, stream>>>(x, n2a, n2b, xn8);

  for (int mc = 0; mc < 4; mc++){
    const uchar* xnc = xn8 + (size_t)mc * 23040 * 256;
    bf16* xc = x + (size_t)mc * 23040 * 256;
    gemm_f8<2><<<2880, 256, 0, stream>>>(xnc, 256, w1f8T, 256, b1, h8, nullptr,
                                         2048, 256, 16, nullptr, nullptr, nullptr);
    gemm_f8<3><<<360, 256, 0, stream>>>(h8, 2048, w2f8T, 2048, b2, nullptr, xc,
                                        256, 2048, 2, nullptr, nullptr, nullptr);
  }

  head_k<<<256, 256, 0, stream>>>(x, src, wl, bl, out);
}

// Round 14
// 682.525 us; speedup vs baseline: 1.4159x; 1.0923x over previous
//
#include <hip/hip_runtime.h>
#include <hip/hip_bf16.h>
#include <math.h>

// ---------------------------------------------------------------------------
// Round 13: gemm_f8 epilogue overhaul. R13: QKV dispatch 75us with MfmaUtil
// 19 / VALU 42 / conflicts 5.3M -> epilogue-bound (64 ds_write_u8/thread,
// ~8-way banks, per-byte f2f8). Fix: swap MFMA operands so each lane holds 4
// consecutive-n values (pack4_fp8 -> 16 ds_write_b32), single-pass staging
// [128][136]=17408B (1 barrier), V as MODE5 (unswapped -> [n][m] staging =
// v^T rows, coalesced stores, no gather). QKV = QK(N=512) + V(N=256).
// ws layout unchanged from R12 (guard 191,365,120 B).
// ---------------------------------------------------------------------------

using bf16 = __hip_bfloat16;
typedef __attribute__((ext_vector_type(4))) float f32x4;
typedef long long i64;
typedef unsigned char uchar;

static __device__ __forceinline__ float wave_sum64(float v){
  #pragma unroll
  for (int o = 32; o >= 1; o >>= 1) v += __shfl_xor(v, o, 64);
  return v;
}

static __device__ __forceinline__ void gl_lds16(const void* g, void* l){
  __builtin_amdgcn_global_load_lds((const __attribute__((address_space(1))) void*)g,
                                   (__attribute__((address_space(3))) void*)l, 16, 0, 0);
}

static __device__ __forceinline__ unsigned pack2(float a, float b){
  union { bf16 h[2]; unsigned u; } u;
  u.h[0] = __float2bfloat16(a); u.h[1] = __float2bfloat16(b);
  return u.u;
}

static __device__ __forceinline__ uchar f2f8(float v){
  return (uchar)(__builtin_amdgcn_cvt_pk_fp8_f32(v, 0.f, 0, false) & 0xff);
}
static __device__ __forceinline__ unsigned pack4_fp8(float a, float b, float c, float d){
  int v = __builtin_amdgcn_cvt_pk_fp8_f32(a, b, 0, false);
  v = __builtin_amdgcn_cvt_pk_fp8_f32(c, d, v, true);
  return (unsigned)v;
}

// merged weight prep: all 6 jobs fp8 transposed. 1280 blocks.
__global__ __launch_bounds__(256) void cvt_all(
    const float* s0, const float* s1, const float* s2, const float* s3,
    const float* s4, const float* s5,
    uchar* d0, uchar* d1, uchar* d2, uchar* d3, uchar* d4, uchar* d5)
{
  __shared__ float t[32][33];
  const float* srcs[6] = {s0, s1, s2, s3, s4, s5};
  uchar* dsts[6] = {d0, d1, d2, d3, d4, d5};
  const int Ks[6] = {256, 256, 256, 256, 256, 2048};
  const int Ns[6] = {256, 256, 256, 256, 2048, 256};
  const int offs[7] = {0, 64, 128, 192, 256, 768, 1280};
  int bid = blockIdx.x, j = 5;
  #pragma unroll
  for (int q = 4; q >= 0; q--) if (bid < offs[q + 1]) j = q;
  int local = bid - offs[j];
  int K = Ks[j], N = Ns[j];
  const float* src = srcs[j];
  uchar* dst = dsts[j];
  int kt = K >> 5;
  int kb = (local % kt) * 32, nb = (local / kt) * 32;
  int tx = threadIdx.x & 31, ty = threadIdx.x >> 5;
  #pragma unroll
  for (int dy = 0; dy < 32; dy += 8)
    t[ty + dy][tx] = src[(size_t)(kb + ty + dy) * N + nb + tx];
  __syncthreads();
  #pragma unroll
  for (int dy = 0; dy < 32; dy += 8)
    dst[(size_t)(nb + ty + dy) * K + kb + tx] = f2f8(t[tx][ty + dy]);
}

// embed + PE + scale -> x (bf16), LN1 -> fp8 xn8. one wave/row, grid 23040.
__global__ __launch_bounds__(256) void embed_ln1(
    const int* __restrict__ src, const float* __restrict__ emb,
    const float* __restrict__ na, const float* __restrict__ nb,
    bf16* __restrict__ x, uchar* __restrict__ xn8)
{
  int row  = blockIdx.x * 4 + (threadIdx.x >> 6);
  int lane = threadIdx.x & 63;
  int s = row % 360;
  int tok = src[row];
  float4 v = *(const float4*)(emb + (size_t)tok * 256 + lane * 4);
  float vv[4] = {v.x, v.y, v.z, v.w};
  if (s < 340){
    const float C = (-2.0f / 256.0f) * 13.287712379549449f;
    #pragma unroll
    for (int t = 0; t < 4; t++){
      int c = lane * 4 + t;
      float ang = (float)s * exp2f(C * (float)c);
      float pe = (c & 1) ? cosf(ang) : sinf(ang);
      vv[t] = 16.0f * vv[t] + pe;
    }
  }
  float sum = wave_sum64(vv[0] + vv[1] + vv[2] + vv[3]);
  float mu = sum * (1.0f / 256.0f);
  float d0 = vv[0]-mu, d1 = vv[1]-mu, d2 = vv[2]-mu, d3 = vv[3]-mu;
  float sq = wave_sum64(d0*d0 + d1*d1 + d2*d2 + d3*d3);
  float inv = 1.0f / (sqrtf(sq * (1.0f / 255.0f)) + 1e-6f);
  bf16 xo[4] = { __float2bfloat16(vv[0]), __float2bfloat16(vv[1]),
                 __float2bfloat16(vv[2]), __float2bfloat16(vv[3]) };
  *(uint2*)(x + (size_t)row * 256 + lane * 4) = *(uint2*)xo;
  float4 a4 = *(const float4*)(na + lane * 4);
  float4 b4 = *(const float4*)(nb + lane * 4);
  unsigned u = pack4_fp8(a4.x * d0 * inv + b4.x, a4.y * d1 * inv + b4.y,
                         a4.z * d2 * inv + b4.z, a4.w * d3 * inv + b4.w);
  *(unsigned*)(xn8 + (size_t)row * 256 + lane * 4) = u;
}

// LN2 over bf16 x -> fp8 xn8. one wave per row. grid 23040.
__global__ __launch_bounds__(256) void ln_k8(
    const bf16* __restrict__ x, const float* __restrict__ na,
    const float* __restrict__ nb, uchar* __restrict__ xn8)
{
  int row  = blockIdx.x * 4 + (threadIdx.x >> 6);
  int lane = threadIdx.x & 63;
  uint2 raw = *(const uint2*)(x + (size_t)row * 256 + lane * 4);
  bf16* xr = (bf16*)&raw;
  float v0 = __bfloat162float(xr[0]), v1 = __bfloat162float(xr[1]);
  float v2 = __bfloat162float(xr[2]), v3 = __bfloat162float(xr[3]);
  float sum = wave_sum64(v0 + v1 + v2 + v3);
  float mu = sum * (1.0f / 256.0f);
  float d0 = v0-mu, d1 = v1-mu, d2 = v2-mu, d3 = v3-mu;
  float sq = wave_sum64(d0*d0 + d1*d1 + d2*d2 + d3*d3);
  float inv = 1.0f / (sqrtf(sq * (1.0f / 255.0f)) + 1e-6f);
  float4 a4 = *(const float4*)(na + lane * 4);
  float4 b4 = *(const float4*)(nb + lane * 4);
  unsigned u = pack4_fp8(a4.x * d0 * inv + b4.x, a4.y * d1 * inv + b4.y,
                         a4.z * d2 * inv + b4.z, a4.w * d3 * inv + b4.w);
  *(unsigned*)(xn8 + (size_t)row * 256 + lane * 4) = u;
}

// fp8 GEMM: C = A[M][K](e4m3) @ Bt[N][K]^T(e4m3). 128x128 tile, BK=64,
// 16B XOR swizzle key (row>>1)&3, XCD remap (grid div 8).
// MODE 2: relu -> fp8 row-major [M][N]          (swapped: rows of D = n)
// MODE 3: bf16 residual in-place += acc (+bias) (swapped)
// MODE 4: QK (N=512): region n0>>8: 0 q8-layout, 1 k8-layout (swapped)
// MODE 5: V  (N=256): v^T8 layout [bh][64][360]  (unswapped, [n][m] staging)
template<int MODE>
__global__ __launch_bounds__(256) void gemm_f8(
    const uchar* __restrict__ A, int lda,
    const uchar* __restrict__ Bt, int ldb,
    const float* __restrict__ bias,
    uchar* __restrict__ out8, bf16* __restrict__ xres,
    int N, int K, int nTiles,
    const float* __restrict__ bq, const float* __restrict__ bk)
{
  __shared__ __align__(16) char smem[17408];   // As 8K | Bs 8K ; staging aliases
  uchar* As = (uchar*)smem;
  uchar* Bs = (uchar*)(smem + 8192);
  uchar* S8 = (uchar*)smem;                    // fp8 staging, stride 136, 128 rows
  bf16 (*Cs)[136] = (bf16 (*)[136])smem;       // bf16 staging (MODE3 halves)
  int chunk = gridDim.x >> 3;
  int bi = (blockIdx.x & 7) * chunk + (blockIdx.x >> 3);
  int m0 = (bi / nTiles) * 128, n0 = (bi % nTiles) * 128;
  int tid = threadIdx.x;
  int wave = tid >> 6, lane = tid & 63;
  int wm = (wave >> 1) * 64, wn = (wave & 1) * 64;
  int r = lane & 15, qd = lane >> 4;

  const uchar* ag[2]; const uchar* bg[2]; uchar* la[2]; uchar* lb[2];
  #pragma unroll
  for (int j = 0; j < 2; j++){
    int c = tid + j * 256;
    int row = c >> 2, pp = c & 3;
    int lco = pp ^ ((row >> 1) & 3);
    ag[j] = A  + (size_t)(m0 + row) * lda + lco * 16;
    bg[j] = Bt + (size_t)(n0 + row) * ldb + lco * 16;
    la[j] = As + (size_t)c * 16;
    lb[j] = Bs + (size_t)c * 16;
  }

  f32x4 acc[4][4];
  #pragma unroll
  for (int mt = 0; mt < 4; mt++)
    #pragma unroll
    for (int nt = 0; nt < 4; nt++) acc[mt][nt] = (f32x4){0.f, 0.f, 0.f, 0.f};

  for (int k0 = 0; k0 < K; k0 += 64){
    #pragma unroll
    for (int j = 0; j < 2; j++){ gl_lds16(ag[j], la[j]); gl_lds16(bg[j], lb[j]); }
    #pragma unroll
    for (int j = 0; j < 2; j++){ ag[j] += 64; bg[j] += 64; }
    __syncthreads();
    #pragma unroll
    for (int ph = 0; ph < 2; ph++){
      int l16 = ph * 2 + (qd >> 1);
      int woff = (qd & 1) * 8;
      i64 af[4], bfr[4];
      #pragma unroll
      for (int t = 0; t < 4; t++){
        int rowA = wm + t * 16 + r;
        int rowB = wn + t * 16 + r;
        int swA = ((l16 ^ ((rowA >> 1) & 3)) * 16) + woff;
        int swB = ((l16 ^ ((rowB >> 1) & 3)) * 16) + woff;
        af[t]  = *(const i64*)(As + rowA * 64 + swA);
        bfr[t] = *(const i64*)(Bs + rowB * 64 + swB);
      }
      #pragma unroll
      for (int mt = 0; mt < 4; mt++)
        #pragma unroll
        for (int nt = 0; nt < 4; nt++){
          if (MODE == 5)
            acc[mt][nt] = __builtin_amdgcn_mfma_f32_16x16x32_fp8_fp8(af[mt], bfr[nt], acc[mt][nt], 0, 0, 0);
          else  // swapped: D rows = n, cols = m
            acc[mt][nt] = __builtin_amdgcn_mfma_f32_16x16x32_fp8_fp8(bfr[nt], af[mt], acc[mt][nt], 0, 0, 0);
        }
    }
    __syncthreads();
  }

  if (MODE == 2 || MODE == 4){
    const int region = (MODE == 4) ? (n0 >> 8) : 0;
    const float* bb = (MODE == 4) ? (region == 0 ? bq : bk) : bias;
    // swapped: lane holds 4 consecutive n (qd*4+i) at fixed m (r). Staging [m][n].
    #pragma unroll
    for (int mt = 0; mt < 4; mt++)
      #pragma unroll
      for (int nt = 0; nt < 4; nt++){
        int ml  = wm + mt * 16 + r;
        int nl0 = wn + nt * 16 + qd * 4;
        int bidx = (MODE == 4) ? ((n0 & 255) + nl0) : (n0 + nl0);
        float v0 = acc[mt][nt][0] + bb[bidx + 0];
        float v1 = acc[mt][nt][1] + bb[bidx + 1];
        float v2 = acc[mt][nt][2] + bb[bidx + 2];
        float v3 = acc[mt][nt][3] + bb[bidx + 3];
        if (MODE == 2){
          v0 = fmaxf(v0, 0.f); v1 = fmaxf(v1, 0.f);
          v2 = fmaxf(v2, 0.f); v3 = fmaxf(v3, 0.f);
        }
        *(unsigned*)(S8 + ml * 136 + nl0) = pack4_fp8(v0, v1, v2, v3);
      }
    __syncthreads();
    int lr = tid >> 1, seg = tid & 1;
    #pragma unroll
    for (int j = 0; j < 4; j++){
      int nl = seg * 64 + j * 16;
      uint2 a = *(uint2*)(S8 + lr * 136 + nl);
      uint2 b = *(uint2*)(S8 + lr * 136 + nl + 8);
      uint4 st = make_uint4(a.x, a.y, b.x, b.y);
      if (MODE == 2){
        *(uint4*)(out8 + (size_t)(m0 + lr) * N + n0 + nl) = st;
      } else {
        int m = m0 + lr;
        int b_ = m / 360, s = m - b_ * 360;
        int nnl = (n0 & 255) + nl;
        int h = nnl >> 6, dk = nnl & 63;
        size_t roff = (region == 1) ? 23592960ull : 0ull;
        *(uint4*)(out8 + roff + ((size_t)(b_ * 4 + h) * 360 + s) * 64 + dk) = st;
      }
    }
  } else if (MODE == 5){
    // unswapped: lane holds 4 consecutive m (qd*4+i) at fixed n (r). Staging [n][m].
    #pragma unroll
    for (int mt = 0; mt < 4; mt++)
      #pragma unroll
      for (int nt = 0; nt < 4; nt++){
        int nl  = wn + nt * 16 + r;
        int ml0 = wm + mt * 16 + qd * 4;
        float bv_ = bias[n0 + nl];
        *(unsigned*)(S8 + nl * 136 + ml0) =
            pack4_fp8(acc[mt][nt][0] + bv_, acc[mt][nt][1] + bv_,
                      acc[mt][nt][2] + bv_, acc[mt][nt][3] + bv_);
      }
    __syncthreads();
    int nn = tid >> 1, part = tid & 1;
    int nnl = n0 + nn;                    // N=256
    int h = nnl >> 6, dk = nnl & 63;
    #pragma unroll
    for (int j0 = 0; j0 < 64; j0 += 8){
      int mm = m0 + part * 64 + j0;       // 8-aligned; 360%8==0 -> no batch cross
      int b_ = mm / 360, s = mm - b_ * 360;
      uint2 val = *(uint2*)(S8 + nn * 136 + part * 64 + j0);
      *(uint2*)(out8 + ((size_t)((b_ * 4 + h) * 64 + dk)) * 360 + s) = val;
    }
  } else {  // MODE 3: bf16 residual, halves, swapped orientation
    #pragma unroll
    for (int half = 0; half < 2; half++){
      if ((wave >> 1) == half){
        #pragma unroll
        for (int mt = 0; mt < 4; mt++)
          #pragma unroll
          for (int nt = 0; nt < 4; nt++){
            int ml  = mt * 16 + r;              // local to half
            int nl0 = wn + nt * 16 + qd * 4;
            float v0 = acc[mt][nt][0] + bias[n0 + nl0 + 0];
            float v1 = acc[mt][nt][1] + bias[n0 + nl0 + 1];
            float v2 = acc[mt][nt][2] + bias[n0 + nl0 + 2];
            float v3 = acc[mt][nt][3] + bias[n0 + nl0 + 3];
            *(unsigned*)(&Cs[ml][nl0])     = pack2(v0, v1);
            *(unsigned*)(&Cs[ml][nl0 + 2]) = pack2(v2, v3);
          }
      }
      __syncthreads();
      int mbase = m0 + half * 64;
      int lr = tid >> 2, seg = tid & 3;
      bf16* op = xres + (size_t)(mbase + lr) * 256 + n0 + seg * 32;
      #pragma unroll
      for (int j = 0; j < 4; j++){
        uint4 cv = *(uint4*)(&Cs[lr][seg * 32 + j * 8]);
        uint4 xv = *(uint4*)(op + j * 8);
        bf16* ca = (bf16*)&cv; bf16* xa = (bf16*)&xv;
        bf16 o8[8];
        #pragma unroll
        for (int t = 0; t < 8; t++)
          o8[t] = __float2bfloat16(__bfloat162float(ca[t]) + __bfloat162float(xa[t]));
        *(uint4*)(op + j * 8) = *(uint4*)o8;
      }
      __syncthreads();
    }
  }
}

// attn5: fp8 flash attention. one block per (b,h) [1024], 512 thr / 8 waves,
// 3 q-tiles/wave, single-pass softmax (pad queries s=0 -> uniform).
__global__ __launch_bounds__(512) void attn5(
    const uchar* __restrict__ q, const uchar* __restrict__ kk, const uchar* __restrict__ vt,
    const int* __restrict__ src, uchar* __restrict__ ctx8)
{
  __shared__ uchar Ks[360][80];
  __shared__ uchar Pb[8][16][48];
  __shared__ uchar Cb[8][16][80];
  int bh = blockIdx.x;
  int b = bh >> 2, h = bh & 3;
  int wave = threadIdx.x >> 6, lane = threadIdx.x & 63;
  int r = lane & 15, qd = lane >> 4;
  const uchar* qb = q  + (size_t)bh * 360 * 64;
  const uchar* kb = kk + (size_t)bh * 360 * 64;
  const uchar* vb = vt + (size_t)bh * 64 * 360;
  const int* srow = src + b * 360;

  for (int c = threadIdx.x; c < 1440; c += 512){
    int row = c >> 2, g = c & 3;
    *(uint4*)(&Ks[row][g * 16]) = *(const uint4*)(kb + row * 64 + g * 16);
  }
  __syncthreads();

  i64 qa0[3], qa1[3];
  bool qp[3];
  float lsum[3];
  f32x4 accO[3][4];
  #pragma unroll
  for (int tl = 0; tl < 3; tl++){
    int qt = wave * 3 + tl;
    int qg = qt * 16 + r;
    int qrow = qg > 359 ? 359 : qg;
    qa0[tl] = *(const i64*)(qb + qrow * 64 + qd * 8);
    qa1[tl] = *(const i64*)(qb + qrow * 64 + 32 + qd * 8);
    qp[tl] = (qg < 360) && (srow[qg] == 799);
    lsum[tl] = 0.f;
    #pragma unroll
    for (int dt = 0; dt < 4; dt++) accO[tl][dt] = (f32x4){0.f, 0.f, 0.f, 0.f};
  }

  for (int kc = 0; kc < 12; kc++){
    int krow0 = kc * 32 + r;      if (krow0 > 359) krow0 = 359;
    int krow1 = kc * 32 + 16 + r; if (krow1 > 359) krow1 = 359;
    i64 kf00 = *(const i64*)(&Ks[krow0][qd * 8]);
    i64 kf01 = *(const i64*)(&Ks[krow0][32 + qd * 8]);
    i64 kf10 = *(const i64*)(&Ks[krow1][qd * 8]);
    i64 kf11 = *(const i64*)(&Ks[krow1][32 + qd * 8]);
    i64 vf[4];
    #pragma unroll
    for (int dt = 0; dt < 4; dt++)
      vf[dt] = *(const i64*)(vb + (size_t)(dt * 16 + r) * 360 + kc * 32 + qd * 8);

    #pragma unroll
    for (int tl = 0; tl < 3; tl++){
      f32x4 z0 = {0.f, 0.f, 0.f, 0.f}, z1 = {0.f, 0.f, 0.f, 0.f};
      z0 = __builtin_amdgcn_mfma_f32_16x16x32_fp8_fp8(kf00, qa0[tl], z0, 0, 0, 0);
      z0 = __builtin_amdgcn_mfma_f32_16x16x32_fp8_fp8(kf01, qa1[tl], z0, 0, 0, 0);
      z1 = __builtin_amdgcn_mfma_f32_16x16x32_fp8_fp8(kf10, qa0[tl], z1, 0, 0, 0);
      z1 = __builtin_amdgcn_mfma_f32_16x16x32_fp8_fp8(kf11, qa1[tl], z1, 0, 0, 0);
      float p0[4], p1[4];
      #pragma unroll
      for (int i = 0; i < 4; i++){
        int key0 = kc * 32 + qd * 4 + i;
        int key1 = key0 + 16;
        float s0 = z0[i] * 0.125f, s1 = z1[i] * 0.125f;
        if (qp[tl]){ s0 = 0.0f; s1 = 0.0f; }
        p0[i] = (key0 < 360) ? __expf(s0) : 0.0f;
        p1[i] = (key1 < 360) ? __expf(s1) : 0.0f;
        lsum[tl] += p0[i] + p1[i];
      }
      *(unsigned*)(&Pb[wave][r][qd * 4])      = pack4_fp8(p0[0], p0[1], p0[2], p0[3]);
      *(unsigned*)(&Pb[wave][r][16 + qd * 4]) = pack4_fp8(p1[0], p1[1], p1[2], p1[3]);
      asm volatile("s_waitcnt lgkmcnt(0)" ::: "memory");
      i64 pa = *(const i64*)(&Pb[wave][r][qd * 8]);
      #pragma unroll
      for (int dt = 0; dt < 4; dt++)
        accO[tl][dt] = __builtin_amdgcn_mfma_f32_16x16x32_fp8_fp8(pa, vf[dt], accO[tl][dt], 0, 0, 0);
      asm volatile("s_waitcnt lgkmcnt(0)" ::: "memory");
    }
  }

  #pragma unroll
  for (int tl = 0; tl < 3; tl++){
    int qt = wave * 3 + tl;
    float ls = lsum[tl];
    ls += __shfl_xor(ls, 16, 64);
    ls += __shfl_xor(ls, 32, 64);
    float invl = 1.0f / ls;
    #pragma unroll
    for (int i = 0; i < 4; i++){
      float inv_i = __shfl(invl, qd * 4 + i, 64);
      #pragma unroll
      for (int dt = 0; dt < 4; dt++)
        Cb[wave][qd * 4 + i][dt * 16 + r] = f2f8(accO[tl][dt][i] * inv_i);
    }
    asm volatile("s_waitcnt lgkmcnt(0)" ::: "memory");
    int qglob = qt * 16 + r;
    if (qglob < 360)
      *(uint4*)(ctx8 + ((size_t)(b * 360 + qglob)) * 256 + h * 64 + qd * 16) =
          *(uint4*)(&Cb[wave][r][qd * 16]);
    asm volatile("s_waitcnt lgkmcnt(0)" ::: "memory");
  }
}

// head: one block per batch (grid 256, 4 waves).
__global__ __launch_bounds__(256) void head_k(
    const bf16* __restrict__ x, const int* __restrict__ src,
    const float* __restrict__ wl, const float* __restrict__ bl,
    float* __restrict__ out)
{
  __shared__ bf16 Xs[192][264];
  int b = blockIdx.x;
  int tid = threadIdx.x;
  int wave = tid >> 6, lane = tid & 63;
  int g = lane >> 3, sub = lane & 7;

  const bf16* xb = x + (size_t)b * 360 * 256;
  for (int it = 0; it < 24; it++){
    int idx = tid + it * 256;
    int row = idx >> 5, col = idx & 31;
    *(uint4*)(&Xs[row][col * 8]) = *(const uint4*)(xb + row * 256 + col * 8);
  }

  float wv[96];
  {
    const float4* wr4 = (const float4*)(wl + (size_t)(g * 256 + sub * 32) * 3);
    #pragma unroll
    for (int c = 0; c < 24; c++) *(float4*)(&wv[c * 4]) = wr4[c];
  }
  float bl0 = bl[0], bl1 = bl[1], bl2 = bl[2];
  const int* sr = src + b * 360;
  __syncthreads();

  for (int p = wave; p < 91; p += 4){
    int i = 0, rem = p;
    while (rem >= 13 - i){ rem -= 13 - i; i++; }
    int j = i + 1 + rem;
    int base = 12 * i - (i * (i - 1)) / 2;
    int pe = base + (j - i) - 1;
    int eb = 28 + 2 * pe;

    int idxg;
    if (g == 0) idxg = 2 * i;
    else if (g == 1) idxg = 2 * i + 1;
    else if (g == 2) idxg = 2 * j;
    else if (g == 3) idxg = 2 * j + 1;
    else idxg = eb + (g - 4);
    bool zm = !(g >= 4 && j == 13);

    uint4 xv[4];
    #pragma unroll
    for (int c = 0; c < 4; c++) xv[c] = *(uint4*)(&Xs[idxg][sub * 32 + c * 8]);
    const bf16* xa = (const bf16*)xv;
    float a0 = 0.f, a1 = 0.f, a2 = 0.f;
    #pragma unroll
    for (int t = 0; t < 32; t++){
      float f = zm ? __bfloat162float(xa[t]) : 0.0f;
      a0 += f * wv[t * 3 + 0];
      a1 += f * wv[t * 3 + 1];
      a2 += f * wv[t * 3 + 2];
    }
    #pragma unroll
    for (int o = 1; o < 64; o <<= 1){
      a0 += __shfl_xor(a0, o, 64);
      a1 += __shfl_xor(a1, o, 64);
      a2 += __shfl_xor(a2, o, 64);
    }
    if (lane == 0){
      int ti = sr[2 * i], ai = sr[2 * i + 1], tj = sr[2 * j], aj = sr[2 * j + 1];
      bool c1 = (ai == 2) || (aj == 2);
      bool c2 = (tj == 1) || (ai == 1) || (aj == 1);
      bool c3 = (ti == 799) || (tj == 799) || (ai == 0) || (aj == 0);
      bool c4 = false;
      if (j < 13){
        int es = 28 + 4 * pe;
        c4 = (sr[es] == 1) || (sr[es + 1] == 1) || (sr[es + 2] == 1) || (sr[es + 3] == 1);
      }
      bool m1 = c3 || c4, m2 = m1 || c2, m3 = m2 || c1;
      float* op = out + ((size_t)b * 91 + p) * 3;
      op[0] = m1 ? -1.0e9f : (a0 + bl0);
      op[1] = m2 ? -1.0e9f : (a1 + bl1);
      op[2] = m3 ? -1.0e9f : (a2 + bl2);
    }
  }
}

extern "C" void kernel_launch(void* const* d_in, const int* in_sizes, int n_in,
                              void* d_out, int out_size, void* d_ws, size_t ws_size,
                              hipStream_t stream)
{
  const int*   src = (const int*)  d_in[0];
  const float* emb = (const float*)d_in[1];
  const float* wq  = (const float*)d_in[2];  const float* bq = (const float*)d_in[3];
  const float* wk  = (const float*)d_in[4];  const float* bk = (const float*)d_in[5];
  const float* wv  = (const float*)d_in[6];  const float* bv = (const float*)d_in[7];
  const float* wo  = (const float*)d_in[8];  const float* bo = (const float*)d_in[9];
  const float* n1a = (const float*)d_in[10]; const float* n1b = (const float*)d_in[11];
  const float* n2a = (const float*)d_in[12]; const float* n2b = (const float*)d_in[13];
  const float* w1  = (const float*)d_in[14]; const float* b1 = (const float*)d_in[15];
  const float* w2  = (const float*)d_in[16]; const float* b2 = (const float*)d_in[17];
  const float* wl  = (const float*)d_in[18]; const float* bl = (const float*)d_in[19];
  float* out = (float*)d_out;

  if (ws_size < 191365120ull) return;

  char* ws = (char*)d_ws;
  bf16*  x    = (bf16*)(ws);                   // [92160][256] bf16
  uchar* xn8  = (uchar*)(ws + 47185920ull);    // [92160][256] fp8: LN1 / ctx8 / LN2
  char*  R    = ws + 70778880ull;
  uchar* q8   = (uchar*)(R);                   // [1024][360][64]; k8 +23592960
  uchar* vt8  = (uchar*)(R + 47185920ull);     // [1024][64][360]
  uchar* h8   = (uchar*)(R);                   // ffn: [23040][2048] fp8
  char*  wC   = ws + 141557760ull;
  uchar* wqkv8 = (uchar*)(wC);                 // [768][256] fp8
  uchar* wo8   = (uchar*)(wC + 196608);        // [256][256] fp8
  uchar* w1f8T = (uchar*)(wC + 262144);        // [2048][256] fp8
  uchar* w2f8T = (uchar*)(wC + 786432);        // [256][2048] fp8

  cvt_all<<<1280, 256, 0, stream>>>(wq, wk, wv, wo, w1, w2,
                                    wqkv8, wqkv8 + 65536, wqkv8 + 131072,
                                    wo8, w1f8T, w2f8T);

  embed_ln1<<<23040, 256, 0, stream>>>(src, emb, n1a, n1b, x, xn8);

  // QK: N=512 (rows 0..511 of wqkv8), 720x4 = 2880 blocks.
  gemm_f8<4><<<2880, 256, 0, stream>>>(xn8, 256, wqkv8, 256, nullptr, q8, nullptr,
                                       512, 256, 4, bq, bk);
  // V: N=256 (rows 512..767), MODE5 -> vt8. 720x2 = 1440 blocks.
  gemm_f8<5><<<1440, 256, 0, stream>>>(xn8, 256, wqkv8 + 131072, 256, bv, vt8, nullptr,
                                       256, 256, 2, nullptr, nullptr);

  attn5<<<1024, 512, 0, stream>>>(q8, q8 + 23592960ull, vt8, src, xn8 /* ctx8 */);

  gemm_f8<3><<<1440, 256, 0, stream>>>(xn8, 256, wo8, 256, bo, nullptr, x,
                                       256, 256, 2, nullptr, nullptr);

  ln_k8<<<23040, 256, 0, stream>>>(x, n2a, n2b, xn8);

  for (int mc = 0; mc < 4; mc++){
    const uchar* xnc = xn8 + (size_t)mc * 23040 * 256;
    bf16* xc = x + (size_t)mc * 23040 * 256;
    gemm_f8<2><<<2880, 256, 0, stream>>>(xnc, 256, w1f8T, 256, b1, h8, nullptr,
                                         2048, 256, 16, nullptr, nullptr);
    gemm_f8<3><<<360, 256, 0, stream>>>(h8, 2048, w2f8T, 2048, b2, nullptr, xc,
                                        256, 2048, 2, nullptr, nullptr);
  }

  head_k<<<256, 256, 0, stream>>>(x, src, wl, bl, out);
}